// Round 13
// baseline (381.639 us; speedup 1.0000x reference)
//
#include <hip/hip_runtime.h>
#include <math.h>

constexpr int NNODES  = 16384;
constexpr int NEDGES  = 131072;
constexpr int NGRAPHS = 16;

typedef short bf16x8 __attribute__((ext_vector_type(8)));
typedef short bf16x4 __attribute__((ext_vector_type(4)));
typedef float f32x4  __attribute__((ext_vector_type(4)));

__device__ __forceinline__ float leaky(float x, float s){ return x >= 0.0f ? x : s * x; }

__device__ __forceinline__ unsigned short f2bf(float f){
  unsigned u = __builtin_bit_cast(unsigned, f);
  u += 0x7FFFu + ((u >> 16) & 1u);          // round-to-nearest-even
  return (unsigned short)(u >> 16);
}
__device__ __forceinline__ float bf2f(unsigned short u){
  unsigned x = (unsigned)u << 16; return __builtin_bit_cast(float, x);
}

__device__ __forceinline__ void gload_lds16(const unsigned short* g, unsigned short* l){
  __builtin_amdgcn_global_load_lds((const __attribute__((address_space(1))) void*)g,
                                   (__attribute__((address_space(3))) void*)l, 16, 0, 0);
}

// ---------------- CSR build (edges fixed across layers; build once) ----------------
__global__ void k_deg(const int* __restrict__ dst, int* __restrict__ deg){
  int e = blockIdx.x * 256 + threadIdx.x;
  if (e < NEDGES) atomicAdd(&deg[dst[e]], 1);
}

__global__ __launch_bounds__(1024) void k_scan(const int* __restrict__ deg,
                                               int* __restrict__ rowptr,
                                               int* __restrict__ cursor){
  __shared__ int sums[1024];
  int t = threadIdx.x;
  int loc[16];
  int s = 0;
  #pragma unroll
  for (int i = 0; i < 16; i++){ loc[i] = deg[t*16 + i]; s += loc[i]; }
  sums[t] = s; __syncthreads();
  for (int off = 1; off < 1024; off <<= 1){
    int v = (t >= off) ? sums[t - off] : 0;
    __syncthreads();
    sums[t] += v;
    __syncthreads();
  }
  int base = (t > 0) ? sums[t-1] : 0;
  #pragma unroll
  for (int i = 0; i < 16; i++){
    rowptr[t*16 + i] = base; cursor[t*16 + i] = base; base += loc[i];
  }
  if (t == 1023) rowptr[NNODES] = base;
}

__global__ void k_scatter(const int* __restrict__ src, const int* __restrict__ dst,
                          int* __restrict__ cursor, int* __restrict__ perm){
  int e = blockIdx.x * 256 + threadIdx.x;
  if (e < NEDGES){ int p = atomicAdd(&cursor[dst[e]], 1); perm[p] = src[e]; }
}

// ---- graph-size counts: LDS histogram per block, one global atomic per (block,graph) ----
__global__ __launch_bounds__(256) void k_counts(const int* __restrict__ gid, float* __restrict__ counts){
  __shared__ int h[NGRAPHS];
  int t = threadIdx.x;
  if (t < NGRAPHS) h[t] = 0;
  __syncthreads();
  int base = blockIdx.x * 1024;
  #pragma unroll
  for (int i = 0; i < 4; i++)
    atomicAdd(&h[gid[base + t + i*256]], 1);
  __syncthreads();
  if (t < NGRAPHS && h[t] > 0) atomicAdd(&counts[t], (float)h[t]);
}

// ---------------- fp32 -> bf16 convert (contiguous) ----------------
__global__ void k_cvt(const float* __restrict__ in, unsigned short* __restrict__ out, int n4){
  int i = blockIdx.x * 256 + threadIdx.x;
  if (i >= n4) return;
  float4 v = ((const float4*)in)[i];
  ushort4 o; o.x = f2bf(v.x); o.y = f2bf(v.y); o.z = f2bf(v.z); o.w = f2bf(v.w);
  ((ushort4*)out)[i] = o;
}

// -------- fp32 [K][NN] -> bf16 transposed [NN][K], both W and RW in one launch --------
__global__ __launch_bounds__(256) void k_cvt_t2(const float* __restrict__ W,
                                                const float* __restrict__ RW,
                                                unsigned short* __restrict__ Wt,
                                                unsigned short* __restrict__ RWt,
                                                int K, int NN){
  __shared__ float tile[32][33];
  const float* src = blockIdx.z ? RW : W;
  unsigned short* dst = blockIdx.z ? RWt : Wt;
  int n0 = blockIdx.x * 32, k0 = blockIdx.y * 32;
  int tx = threadIdx.x & 31, ty = threadIdx.x >> 5;   // 32 x 8
  #pragma unroll
  for (int i = 0; i < 4; i++)
    tile[ty + i*8][tx] = src[(size_t)(k0 + ty + i*8) * NN + n0 + tx];
  __syncthreads();
  #pragma unroll
  for (int i = 0; i < 4; i++)
    dst[(size_t)(n0 + ty + i*8) * K + k0 + tx] = f2bf(tile[tx][ty + i*8]);
}

// ------- fused dual bf16 MFMA GEMM: H = A@Wt^T, R = A@RWt^T (both bf16 out) -------
// 128x128 tile, BK=64. A: LDS double-buffered via global_load_lds (32KB total ->
// 5 blocks/CU, 20 waves/CU). B: weights are small + L2-resident (reused by all
// row-blocks on the XCD after swizzle) -> read fragments DIRECTLY from global,
// no LDS staging. One barrier per K-step. W-half epilogue: el/er partials.
__global__ __launch_bounds__(256) void k_gemm2(const unsigned short* __restrict__ A,
                                               const unsigned short* __restrict__ Wt,
                                               const unsigned short* __restrict__ RWt,
                                               unsigned short* __restrict__ HB,
                                               unsigned short* __restrict__ RB,
                                               const float* __restrict__ al,
                                               const float* __restrict__ ar,
                                               float* __restrict__ elp,
                                               float* __restrict__ erp,
                                               int K, int NN){
  __shared__ unsigned short As[2][128 * 64];
  int t = threadIdx.x;
  int lane = t & 63, w = t >> 6;
  int nx  = gridDim.x;                       // 2*NN/128
  int nwg = nx * gridDim.y;                  // multiple of 8
  int bid = blockIdx.x + blockIdx.y * nx;
  int wg  = (bid & 7) * (nwg >> 3) + (bid >> 3);
  int bx = wg % nx, by = wg / nx;
  int half = nx >> 1;
  bool isW = bx < half;
  const unsigned short* Bt = isW ? Wt : RWt;
  int colB = (isW ? bx : bx - half) * 128;
  int rowA = by * 128;

  int wr = (w >> 1) * 64, wc = (w & 1) * 64;
  int l16 = lane & 15, lhi = lane >> 4;
  int r8  = lane >> 3;
  int kcs = (((lane & 7) * 16) ^ (r8 << 4)) >> 1;   // shorts, lane-constant
  f32x4 acc[4][4] = {};

  const unsigned short* Ap = A + (size_t)(rowA) * K + kcs;
  // per-lane base pointers for the 4 B-fragment rows this wave reads
  const unsigned short* Bp[4];
  #pragma unroll
  for (int ni = 0; ni < 4; ni++)
    Bp[ni] = Bt + (size_t)(colB + wc + ni * 16 + l16) * K + lhi * 8;

  int nt = K >> 6;
  // prologue: stage A tile 0 into buf 0
  #pragma unroll
  for (int i = 0; i < 4; i++){
    int c = w * 4 + i;
    int row = c * 8 + r8;
    gload_lds16(Ap + (size_t)row * K, &As[0][c * 512]);
  }
  __syncthreads();

  int cur = 0;
  for (int tI = 0; tI < nt; tI++){
    int k0 = tI << 6;
    // B fragments direct from global/L2 (issue first: latency hides under ds_reads)
    bf16x8 bfr[4][2];
    #pragma unroll
    for (int ni = 0; ni < 4; ni++){
      bfr[ni][0] = *(const bf16x8*)(Bp[ni] + k0);
      bfr[ni][1] = *(const bf16x8*)(Bp[ni] + k0 + 32);
    }
    // prefetch next A tile into other buffer
    if (tI + 1 < nt){
      int k0n = k0 + 64;
      #pragma unroll
      for (int i = 0; i < 4; i++){
        int c = w * 4 + i;
        int row = c * 8 + r8;
        gload_lds16(Ap + (size_t)row * K + k0n, &As[cur ^ 1][c * 512]);
      }
    }
    // A fragments from LDS
    bf16x8 af[4][2];
    #pragma unroll
    for (int mi = 0; mi < 4; mi++){
      int row = wr + mi * 16 + l16;
      #pragma unroll
      for (int s = 0; s < 2; s++){
        int k = s * 32 + lhi * 8;
        int off = row * 128 + ((k * 2) ^ ((row & 7) << 4));
        af[mi][s] = *(const bf16x8*)((const char*)As[cur] + off);
      }
    }
    #pragma unroll
    for (int mi = 0; mi < 4; mi++)
      #pragma unroll
      for (int ni = 0; ni < 4; ni++){
        acc[mi][ni] = __builtin_amdgcn_mfma_f32_16x16x32_bf16(af[mi][0], bfr[ni][0], acc[mi][ni], 0, 0, 0);
        acc[mi][ni] = __builtin_amdgcn_mfma_f32_16x16x32_bf16(af[mi][1], bfr[ni][1], acc[mi][ni], 0, 0, 0);
      }
    __syncthreads();
    cur ^= 1;
  }

  unsigned short* C = isW ? HB : RB;
  #pragma unroll
  for (int mi = 0; mi < 4; mi++){
    #pragma unroll
    for (int j = 0; j < 4; j++){
      int r = rowA + wr + mi * 16 + lhi * 4 + j;
      unsigned short* Cp = C + (size_t)r * NN + colB + wc + l16;
      #pragma unroll
      for (int ni = 0; ni < 4; ni++)
        Cp[ni * 16] = f2bf(acc[mi][ni][j]);
    }
  }

  if (isW){
    // el/er partials over this wave's 64 columns; plain stores (no atomics).
    int G = NN >> 6;                    // 64-col groups across nn
    int g64 = (colB + wc) >> 6;
    float alv[4], arv[4];
    #pragma unroll
    for (int ni = 0; ni < 4; ni++){
      int col = colB + wc + ni * 16 + l16;
      alv[ni] = al[col]; arv[ni] = ar[col];
    }
    #pragma unroll
    for (int mi = 0; mi < 4; mi++){
      #pragma unroll
      for (int j = 0; j < 4; j++){
        float pe = acc[mi][0][j]*alv[0] + acc[mi][1][j]*alv[1]
                 + acc[mi][2][j]*alv[2] + acc[mi][3][j]*alv[3];
        float pr = acc[mi][0][j]*arv[0] + acc[mi][1][j]*arv[1]
                 + acc[mi][2][j]*arv[2] + acc[mi][3][j]*arv[3];
        #pragma unroll
        for (int o = 8; o; o >>= 1){ pe += __shfl_xor(pe, o); pr += __shfl_xor(pr, o); }
        if (l16 == 0){
          int r = rowA + wr + mi * 16 + lhi * 4 + j;
          elp[(size_t)r * G + g64] = pe;
          erp[(size_t)r * G + g64] = pr;
        }
      }
    }
  }
}

// ---- reduce el/er partials: one thread per row; G = nn/64, half per head ----
__global__ void k_elred(const float* __restrict__ elp, const float* __restrict__ erp,
                        float* __restrict__ el, float* __restrict__ er, int G){
  int row = blockIdx.x * 256 + threadIdx.x;
  int half = G >> 1;
  float s0 = 0.f, s1 = 0.f, q0 = 0.f, q1 = 0.f;
  const float* ep = elp + (size_t)row * G;
  const float* rp = erp + (size_t)row * G;
  for (int i = 0; i < half; i++){ s0 += ep[i]; q0 += rp[i]; }
  for (int i = half; i < G; i++){ s1 += ep[i]; q1 += rp[i]; }
  el[row*2] = s0; el[row*2+1] = s1;
  er[row*2] = q0; er[row*2+1] = q1;
}

// ---------------- attention: one wave per destination node; RB(bf16) += attn ----------------
template<int D>
__global__ __launch_bounds__(256) void k_attn(const unsigned short* __restrict__ HB,
                                              unsigned short* __restrict__ RB,
                                              const float* __restrict__ el,
                                              const float* __restrict__ er,
                                              const int* __restrict__ rowptr,
                                              const int* __restrict__ perm){
  constexpr int ITER = (2*D)/256;
  int wid = threadIdx.x >> 6, lane = threadIdx.x & 63;
  int nb = (blockIdx.x & 7) * (NNODES/4/8) + (blockIdx.x >> 3);   // bijective: 4096 = 8*512
  int n = nb * 4 + wid;
  int r0 = rowptr[n], r1 = rowptr[n+1];
  if (r0 == r1) return;   // no in-edges: output = residual already in RB
  float er0 = er[n*2], er1 = er[n*2+1];
  float mx0 = -1e30f, mx1 = -1e30f;
  for (int e = r0 + lane; e < r1; e += 64){
    int s = perm[e];
    mx0 = fmaxf(mx0, leaky(el[s*2]   + er0, 0.2f));
    mx1 = fmaxf(mx1, leaky(el[s*2+1] + er1, 0.2f));
  }
  #pragma unroll
  for (int o = 32; o; o >>= 1){ mx0 = fmaxf(mx0, __shfl_xor(mx0, o)); mx1 = fmaxf(mx1, __shfl_xor(mx1, o)); }
  float sm0 = 0.0f, sm1 = 0.0f;
  for (int e = r0 + lane; e < r1; e += 64){
    int s = perm[e];
    sm0 += expf(leaky(el[s*2]   + er0, 0.2f) - mx0);
    sm1 += expf(leaky(el[s*2+1] + er1, 0.2f) - mx1);
  }
  #pragma unroll
  for (int o = 32; o; o >>= 1){ sm0 += __shfl_xor(sm0, o); sm1 += __shfl_xor(sm1, o); }
  float inv0 = 1.0f / sm0, inv1 = 1.0f / sm1;
  float acc[ITER][4];
  #pragma unroll
  for (int j = 0; j < ITER; j++)
    #pragma unroll
    for (int i = 0; i < 4; i++) acc[j][i] = 0.0f;
  for (int e = r0; e < r1; ++e){
    int s = perm[e];
    float a0 = expf(leaky(el[s*2]   + er0, 0.2f) - mx0) * inv0;
    float a1 = expf(leaky(el[s*2+1] + er1, 0.2f) - mx1) * inv1;
    const unsigned short* hrow = HB + (size_t)s * (2*D);
    #pragma unroll
    for (int j = 0; j < ITER; j++){
      int base = j*256 + lane*4;
      bf16x4 v = *(const bf16x4*)(hrow + base);
      float a = (base < D) ? a0 : a1;
      #pragma unroll
      for (int i = 0; i < 4; i++)
        acc[j][i] += a * bf2f((unsigned short)v[i]);
    }
  }
  unsigned short* rrow = RB + (size_t)n * (2*D);
  #pragma unroll
  for (int j = 0; j < ITER; j++){
    int base = j*256 + lane*4;
    bf16x4 r = *(bf16x4*)(rrow + base);
    ushort4 o;
    o.x = f2bf(bf2f((unsigned short)r[0]) + acc[j][0]);
    o.y = f2bf(bf2f((unsigned short)r[1]) + acc[j][1]);
    o.z = f2bf(bf2f((unsigned short)r[2]) + acc[j][2]);
    o.w = f2bf(bf2f((unsigned short)r[3]) + acc[j][3]);
    *(ushort4*)(rrow + base) = o;
  }
}

// ------- GraphNorm stats (bf16 in): grid (NNODES/128, nn/256); lane owns 4 cols -------
__global__ __launch_bounds__(256) void k_stats(const unsigned short* __restrict__ R, int nn,
                                               float* __restrict__ gsum, float* __restrict__ gsq){
  int t = threadIdx.x, lane = t & 63, w = t >> 6;
  int c = blockIdx.y * 256 + lane * 4;
  const unsigned short* base = R + (size_t)(blockIdx.x * 128 + w) * nn + c;
  float4 s = make_float4(0,0,0,0), q = make_float4(0,0,0,0);
  #pragma unroll 4
  for (int i = 0; i < 32; i++){
    bf16x4 bv = *(const bf16x4*)(base + (size_t)(i * 4) * nn);
    float vx = bf2f((unsigned short)bv[0]), vy = bf2f((unsigned short)bv[1]);
    float vz = bf2f((unsigned short)bv[2]), vw = bf2f((unsigned short)bv[3]);
    s.x += vx; s.y += vy; s.z += vz; s.w += vw;
    q.x += vx*vx; q.y += vy*vy; q.z += vz*vz; q.w += vw*vw;
  }
  __shared__ float4 rs[256], rq[256];
  rs[t] = s; rq[t] = q; __syncthreads();
  if (t < 64){
    float4 a = rs[t], b = rs[t+64], c2 = rs[t+128], d2 = rs[t+192];
    float4 e = rq[t], f = rq[t+64], g2 = rq[t+128], h2 = rq[t+192];
    int cc = blockIdx.y * 256 + t * 4;
    atomicAdd(&gsum[cc+0], a.x+b.x+c2.x+d2.x);
    atomicAdd(&gsum[cc+1], a.y+b.y+c2.y+d2.y);
    atomicAdd(&gsum[cc+2], a.z+b.z+c2.z+d2.z);
    atomicAdd(&gsum[cc+3], a.w+b.w+c2.w+d2.w);
    atomicAdd(&gsq [cc+0], e.x+f.x+g2.x+h2.x);
    atomicAdd(&gsq [cc+1], e.y+f.y+g2.y+h2.y);
    atomicAdd(&gsq [cc+2], e.z+f.z+g2.z+h2.z);
    atomicAdd(&gsq [cc+3], e.w+f.w+g2.w+h2.w);
  }
}

// -- norm apply + leaky + head-mean pool (bf16 in) with INLINE stats finalize --
// grid (NNODES/128, nn/256); params are d-length; column c -> channel c & (d-1).
__global__ __launch_bounds__(256) void k_norm_pool(const unsigned short* __restrict__ R,
                                                   unsigned short* __restrict__ Xn, // bf16 next-layer input (or null)
                                                   const float* __restrict__ gsum,
                                                   const float* __restrict__ gsq,
                                                   const float* __restrict__ gamma,
                                                   const float* __restrict__ beta,
                                                   const float* __restrict__ alpha,
                                                   float* __restrict__ pool, int d, int loff){
  int t = threadIdx.x, lane = t & 63, w = t >> 6;
  int c = blockIdx.y * 256 + lane * 4;
  int cm = c & (d - 1);                    // channel index (d-periodic), 4-aligned
  int nodeb = blockIdx.x * 128;
  int g = blockIdx.x >> 3;                 // 8 row-blocks per graph (1024 nodes/graph)
  int nn = 2 * d;
  const float Minv = 1.0f / (2.0f * (float)NNODES);
  float4 gg = *(const float4*)(gamma + cm);
  float4 bb = *(const float4*)(beta + cm);
  float4 aa = *(const float4*)(alpha + cm);
  float mmv[4], rrv[4];
  #pragma unroll
  for (int i = 0; i < 4; i++){
    float m = (gsum[cm+i] + gsum[cm+i+d]) * Minv;
    float q = (gsq [cm+i] + gsq [cm+i+d]) * Minv;
    float a = (i==0)?aa.x:(i==1)?aa.y:(i==2)?aa.z:aa.w;
    float var = q - a * m * m * (2.0f - a);
    mmv[i] = m; rrv[i] = rsqrtf(var + 1e-5f);
  }
  float am0 = aa.x*mmv[0], am1 = aa.y*mmv[1], am2 = aa.z*mmv[2], am3 = aa.w*mmv[3];
  const unsigned short* base = R + (size_t)(nodeb + w) * nn + c;
  unsigned short* xb = Xn ? (Xn + (size_t)(nodeb + w) * nn + c) : nullptr;
  float4 accp = make_float4(0,0,0,0);
  #pragma unroll 4
  for (int i = 0; i < 32; i++){
    bf16x4 bv = *(const bf16x4*)(base + (size_t)(i * 4) * nn);
    float vx = bf2f((unsigned short)bv[0]), vy = bf2f((unsigned short)bv[1]);
    float vz = bf2f((unsigned short)bv[2]), vw = bf2f((unsigned short)bv[3]);
    float y0 = gg.x*(vx-am0)*rrv[0] + bb.x; y0 = y0 >= 0.f ? y0 : 0.01f*y0;
    float y1 = gg.y*(vy-am1)*rrv[1] + bb.y; y1 = y1 >= 0.f ? y1 : 0.01f*y1;
    float y2 = gg.z*(vz-am2)*rrv[2] + bb.z; y2 = y2 >= 0.f ? y2 : 0.01f*y2;
    float y3 = gg.w*(vw-am3)*rrv[3] + bb.w; y3 = y3 >= 0.f ? y3 : 0.01f*y3;
    if (xb){
      ushort4 o; o.x = f2bf(y0); o.y = f2bf(y1); o.z = f2bf(y2); o.w = f2bf(y3);
      *(ushort4*)(xb + (size_t)(i * 4) * nn) = o;
    }
    accp.x += y0; accp.y += y1; accp.z += y2; accp.w += y3;
  }
  __shared__ float4 red[256];
  red[t] = accp; __syncthreads();
  if (t < 64){
    float4 a = red[t], b = red[t+64], c2 = red[t+128], d2 = red[t+192];
    int cc = blockIdx.y * 256 + t * 4;
    float* pb = pool + g * 896 + loff;
    atomicAdd(&pb[(cc+0) & (d-1)], 0.5f*(a.x+b.x+c2.x+d2.x));
    atomicAdd(&pb[(cc+1) & (d-1)], 0.5f*(a.y+b.y+c2.y+d2.y));
    atomicAdd(&pb[(cc+2) & (d-1)], 0.5f*(a.z+b.z+c2.z+d2.z));
    atomicAdd(&pb[(cc+3) & (d-1)], 0.5f*(a.w+b.w+c2.w+d2.w));
  }
}

__global__ void k_final(const float* __restrict__ pool, const float* __restrict__ counts,
                        float* __restrict__ out){
  int idx = blockIdx.x * 256 + threadIdx.x;
  if (idx >= NGRAPHS * 896) return;
  int g = idx / 896;
  float v = pool[idx] / counts[g];
  out[idx] = v >= 0.0f ? v : 0.01f * v;
}

// ---------------------------------------------------------------------------------------
extern "C" void kernel_launch(void* const* d_in, const int* in_sizes, int n_in,
                              void* d_out, int out_size, void* d_ws, size_t ws_size,
                              hipStream_t stream){
  const float* x0 = (const float*)d_in[0];
  const float *W[3], *AL[3], *AR[3], *RW[3], *GA[3], *BE[3], *ALP[3];
  for (int l = 0; l < 3; l++){
    const int b = 1 + l*7;
    W[l]  = (const float*)d_in[b+0];
    AL[l] = (const float*)d_in[b+1];
    AR[l] = (const float*)d_in[b+2];
    RW[l] = (const float*)d_in[b+3];
    GA[l] = (const float*)d_in[b+4];
    BE[l] = (const float*)d_in[b+5];
    ALP[l]= (const float*)d_in[b+6];
  }
  const int* esrc = (const int*)d_in[22];
  const int* edst = (const int*)d_in[23];
  const int* gid  = (const int*)d_in[24];
  float* out = (float*)d_out;

  char* p = (char*)d_ws;
  auto carve = [&](size_t bytes)->void*{
    void* r = (void*)p; p += (bytes + 255) & ~(size_t)255; return r;
  };
  unsigned short* HB = (unsigned short*)carve((size_t)NNODES * 1024 * 2);  // h bf16 [N, 2d]
  unsigned short* RB = (unsigned short*)carve((size_t)NNODES * 1024 * 2);  // r/out bf16 [N, 2d]
  unsigned short* X0b = (unsigned short*)carve((size_t)NNODES * 128 * 2);  // bf16 layer-0 input
  unsigned short* XA  = (unsigned short*)carve((size_t)NNODES * 256 * 2);  // bf16 y0
  unsigned short* XB  = (unsigned short*)carve((size_t)NNODES * 512 * 2);  // bf16 y1
  unsigned short* Wt  = (unsigned short*)carve((size_t)1024 * 512 * 2);    // bf16 W^T (max)
  unsigned short* RWt = (unsigned short*)carve((size_t)1024 * 512 * 2);    // bf16 resW^T (max)
  float* el     = (float*)carve((size_t)NNODES * 2 * 4);
  float* er     = (float*)carve((size_t)NNODES * 2 * 4);
  float* elp    = (float*)carve((size_t)NNODES * 16 * 4);    // el partials (G<=16)
  float* erp    = (float*)carve((size_t)NNODES * 16 * 4);    // er partials
  int*   deg    = (int*)  carve((size_t)NNODES * 4);
  int*   rowptr = (int*)  carve((size_t)(NNODES + 1) * 4);
  int*   cursor = (int*)  carve((size_t)NNODES * 4);
  int*   perm   = (int*)  carve((size_t)NEDGES * 4);
  float* stats  = (float*)carve(2048 * 4);                   // gsum[1024] | gsq[1024]
  float* pool   = (float*)carve((size_t)NGRAPHS * 896 * 4);
  float* countsF= (float*)carve((size_t)NGRAPHS * 4);
  (void)ws_size; (void)in_sizes; (void)n_in; (void)out_size;

  hipMemsetAsync(deg, 0, NNODES * 4, stream);
  hipMemsetAsync(pool, 0, NGRAPHS * 896 * 4, stream);
  hipMemsetAsync(countsF, 0, NGRAPHS * 4, stream);

  k_deg    <<<NEDGES/256, 256, 0, stream>>>(edst, deg);
  k_scan   <<<1, 1024, 0, stream>>>(deg, rowptr, cursor);
  k_scatter<<<NEDGES/256, 256, 0, stream>>>(esrc, edst, cursor, perm);
  k_counts <<<NNODES/1024, 256, 0, stream>>>(gid, countsF);
  k_cvt    <<<(NNODES*128/4 + 255)/256, 256, 0, stream>>>(x0, X0b, NNODES*128/4);

  const unsigned short* xin = X0b;
  int loff = 0;
  const int dims[3] = {128, 256, 512};
  for (int l = 0; l < 3; l++){
    int d = dims[l], nn = 2*d;
    dim3 gt(nn/32, d/32, 2);
    k_cvt_t2<<<gt, 256, 0, stream>>>(W[l], RW[l], Wt, RWt, d, nn);
    dim3 gg(2*nn/128, NNODES/128);
    k_gemm2<<<gg, 256, 0, stream>>>(xin, Wt, RWt, HB, RB, AL[l], AR[l], elp, erp, d, nn);
    k_elred<<<NNODES/256, 256, 0, stream>>>(elp, erp, el, er, nn >> 6);
    if (d == 128){
      k_attn<128><<<NNODES/4, 256, 0, stream>>>(HB, RB, el, er, rowptr, perm);
    } else if (d == 256){
      k_attn<256><<<NNODES/4, 256, 0, stream>>>(HB, RB, el, er, rowptr, perm);
    } else {
      k_attn<512><<<NNODES/4, 256, 0, stream>>>(HB, RB, el, er, rowptr, perm);
    }
    hipMemsetAsync(stats, 0, 2048 * 4, stream);
    dim3 gs(NNODES/128, nn/256);
    k_stats   <<<gs, 256, 0, stream>>>(RB, nn, stats, stats + 1024);
    unsigned short* xn = (l == 0) ? XA : (l == 1) ? XB : nullptr;
    k_norm_pool<<<gs, 256, 0, stream>>>(RB, xn, stats, stats + 1024, GA[l], BE[l], ALP[l], pool, d, loff);
    xin = xn; loff += d;
  }
  k_final<<<(NGRAPHS*896 + 255)/256, 256, 0, stream>>>(pool, countsF, out);
}

// Round 14
// 355.423 us; speedup vs baseline: 1.0738x; 1.0738x over previous
//
#include <hip/hip_runtime.h>
#include <math.h>

constexpr int NNODES  = 16384;
constexpr int NEDGES  = 131072;
constexpr int NGRAPHS = 16;

typedef short bf16x8 __attribute__((ext_vector_type(8)));
typedef short bf16x4 __attribute__((ext_vector_type(4)));
typedef float f32x4  __attribute__((ext_vector_type(4)));

__device__ __forceinline__ float leaky(float x, float s){ return x >= 0.0f ? x : s * x; }

__device__ __forceinline__ unsigned short f2bf(float f){
  unsigned u = __builtin_bit_cast(unsigned, f);
  u += 0x7FFFu + ((u >> 16) & 1u);          // round-to-nearest-even
  return (unsigned short)(u >> 16);
}
__device__ __forceinline__ float bf2f(unsigned short u){
  unsigned x = (unsigned)u << 16; return __builtin_bit_cast(float, x);
}

__device__ __forceinline__ void gload_lds16(const unsigned short* g, unsigned short* l){
  __builtin_amdgcn_global_load_lds((const __attribute__((address_space(1))) void*)g,
                                   (__attribute__((address_space(3))) void*)l, 16, 0, 0);
}

// ---------------- CSR build (edges fixed across layers; build once) ----------------
__global__ void k_deg(const int* __restrict__ dst, int* __restrict__ deg){
  int e = blockIdx.x * 256 + threadIdx.x;
  if (e < NEDGES) atomicAdd(&deg[dst[e]], 1);
}

__global__ __launch_bounds__(1024) void k_scan(const int* __restrict__ deg,
                                               int* __restrict__ rowptr,
                                               int* __restrict__ cursor){
  __shared__ int sums[1024];
  int t = threadIdx.x;
  int loc[16];
  int s = 0;
  #pragma unroll
  for (int i = 0; i < 16; i++){ loc[i] = deg[t*16 + i]; s += loc[i]; }
  sums[t] = s; __syncthreads();
  for (int off = 1; off < 1024; off <<= 1){
    int v = (t >= off) ? sums[t - off] : 0;
    __syncthreads();
    sums[t] += v;
    __syncthreads();
  }
  int base = (t > 0) ? sums[t-1] : 0;
  #pragma unroll
  for (int i = 0; i < 16; i++){
    rowptr[t*16 + i] = base; cursor[t*16 + i] = base; base += loc[i];
  }
  if (t == 1023) rowptr[NNODES] = base;
}

__global__ void k_scatter(const int* __restrict__ src, const int* __restrict__ dst,
                          int* __restrict__ cursor, int* __restrict__ perm){
  int e = blockIdx.x * 256 + threadIdx.x;
  if (e < NEDGES){ int p = atomicAdd(&cursor[dst[e]], 1); perm[p] = src[e]; }
}

// ---- graph-size counts: LDS histogram per block, one global atomic per (block,graph) ----
__global__ __launch_bounds__(256) void k_counts(const int* __restrict__ gid, float* __restrict__ counts){
  __shared__ int h[NGRAPHS];
  int t = threadIdx.x;
  if (t < NGRAPHS) h[t] = 0;
  __syncthreads();
  int base = blockIdx.x * 1024;
  #pragma unroll
  for (int i = 0; i < 4; i++)
    atomicAdd(&h[gid[base + t + i*256]], 1);
  __syncthreads();
  if (t < NGRAPHS && h[t] > 0) atomicAdd(&counts[t], (float)h[t]);
}

// ---------------- fp32 -> bf16 convert (contiguous) ----------------
__global__ void k_cvt(const float* __restrict__ in, unsigned short* __restrict__ out, int n4){
  int i = blockIdx.x * 256 + threadIdx.x;
  if (i >= n4) return;
  float4 v = ((const float4*)in)[i];
  ushort4 o; o.x = f2bf(v.x); o.y = f2bf(v.y); o.z = f2bf(v.z); o.w = f2bf(v.w);
  ((ushort4*)out)[i] = o;
}

// -------- fp32 [K][NN] -> bf16 transposed [NN][K], both W and RW in one launch --------
__global__ __launch_bounds__(256) void k_cvt_t2(const float* __restrict__ W,
                                                const float* __restrict__ RW,
                                                unsigned short* __restrict__ Wt,
                                                unsigned short* __restrict__ RWt,
                                                int K, int NN){
  __shared__ float tile[32][33];
  const float* src = blockIdx.z ? RW : W;
  unsigned short* dst = blockIdx.z ? RWt : Wt;
  int n0 = blockIdx.x * 32, k0 = blockIdx.y * 32;
  int tx = threadIdx.x & 31, ty = threadIdx.x >> 5;   // 32 x 8
  #pragma unroll
  for (int i = 0; i < 4; i++)
    tile[ty + i*8][tx] = src[(size_t)(k0 + ty + i*8) * NN + n0 + tx];
  __syncthreads();
  #pragma unroll
  for (int i = 0; i < 4; i++)
    dst[(size_t)(n0 + ty + i*8) * K + k0 + tx] = f2bf(tile[tx][ty + i*8]);
}

// ---- Wal[k][4] = {Σ_c<d W[k][c]al[c], Σ_c>=d W[k][c]al[c], same with ar} ----
// el/er are linear in h: el[n,h] = x[n,:] @ Wal_h. One wave per k-row.
__global__ __launch_bounds__(256) void k_wal(const float* __restrict__ W,
                                             const float* __restrict__ al,
                                             const float* __restrict__ ar,
                                             float* __restrict__ Wal, int K, int NN){
  int wid = threadIdx.x >> 6, lane = threadIdx.x & 63;
  int k = blockIdx.x * 4 + wid;
  if (k >= K) return;
  const float* wr_ = W + (size_t)k * NN;
  int d = NN >> 1;
  float e0 = 0.f, e1 = 0.f, r0 = 0.f, r1 = 0.f;
  for (int c = lane; c < NN; c += 64){
    float wv = wr_[c];
    float av = al[c], rv = ar[c];
    if (c < d){ e0 += wv*av; r0 += wv*rv; } else { e1 += wv*av; r1 += wv*rv; }
  }
  #pragma unroll
  for (int o = 32; o; o >>= 1){
    e0 += __shfl_xor(e0, o); e1 += __shfl_xor(e1, o);
    r0 += __shfl_xor(r0, o); r1 += __shfl_xor(r1, o);
  }
  if (lane == 0){
    Wal[k*4+0] = e0; Wal[k*4+1] = e1; Wal[k*4+2] = r0; Wal[k*4+3] = r1;
  }
}

// ---- el/er = X(bf16)[N,K] @ Wal[K,4]: one wave per node ----
__global__ __launch_bounds__(256) void k_elxw(const unsigned short* __restrict__ X,
                                              const float* __restrict__ Wal,
                                              float* __restrict__ el, float* __restrict__ er,
                                              int K){
  int wid = threadIdx.x >> 6, lane = threadIdx.x & 63;
  int n = blockIdx.x * 4 + wid;
  const unsigned short* xr = X + (size_t)n * K;
  float e0 = 0.f, e1 = 0.f, r0 = 0.f, r1 = 0.f;
  for (int c = lane*4; c < K; c += 256){
    bf16x4 v = *(const bf16x4*)(xr + c);
    #pragma unroll
    for (int i = 0; i < 4; i++){
      float xv = bf2f((unsigned short)v[i]);
      float4 wv = *(const float4*)(Wal + (size_t)(c+i)*4);
      e0 += xv*wv.x; e1 += xv*wv.y; r0 += xv*wv.z; r1 += xv*wv.w;
    }
  }
  #pragma unroll
  for (int o = 32; o; o >>= 1){
    e0 += __shfl_xor(e0, o); e1 += __shfl_xor(e1, o);
    r0 += __shfl_xor(r0, o); r1 += __shfl_xor(r1, o);
  }
  if (lane == 0){
    el[n*2] = e0; el[n*2+1] = e1; er[n*2] = r0; er[n*2+1] = r1;
  }
}

// ------- fused dual bf16 MFMA GEMM (R10 structure): H = A@Wt^T, R = A@RWt^T -------
// 128x128 tile, BK=64, 2-phase double-buffered LDS, one barrier per K-step,
// global_load_lds staging (linear dest, pre-swizzled source), XCD-aware swizzle.
__global__ __launch_bounds__(256) void k_gemm2(const unsigned short* __restrict__ A,
                                               const unsigned short* __restrict__ Wt,
                                               const unsigned short* __restrict__ RWt,
                                               unsigned short* __restrict__ HB,
                                               unsigned short* __restrict__ RB,
                                               int K, int NN){
  __shared__ unsigned short As[2][128 * 64];
  __shared__ unsigned short Bs[2][128 * 64];
  int t = threadIdx.x;
  int lane = t & 63, w = t >> 6;
  int nx  = gridDim.x;                       // 2*NN/128
  int nwg = nx * gridDim.y;                  // multiple of 8
  int bid = blockIdx.x + blockIdx.y * nx;
  int wg  = (bid & 7) * (nwg >> 3) + (bid >> 3);
  int bx = wg % nx, by = wg / nx;
  int half = nx >> 1;
  bool isW = bx < half;
  const unsigned short* Bt = isW ? Wt : RWt;
  int colB = (isW ? bx : bx - half) * 128;
  int rowA = by * 128;

  int wr = (w >> 1) * 64, wc = (w & 1) * 64;
  int l16 = lane & 15, lhi = lane >> 4;
  int r8  = lane >> 3;
  int kcs = (((lane & 7) * 16) ^ (r8 << 4)) >> 1;   // shorts, lane-constant
  f32x4 acc[4][4] = {};

  const unsigned short* Ap = A  + (size_t)(rowA) * K + kcs;
  const unsigned short* Bp = Bt + (size_t)(colB) * K + kcs;

  int nt = K >> 6;
  #pragma unroll
  for (int i = 0; i < 4; i++){
    int c = w * 4 + i;
    int row = c * 8 + r8;
    gload_lds16(Ap + (size_t)row * K, &As[0][c * 512]);
    gload_lds16(Bp + (size_t)row * K, &Bs[0][c * 512]);
  }
  __syncthreads();

  int cur = 0;
  for (int tI = 0; tI < nt; tI++){
    if (tI + 1 < nt){
      int k0n = (tI + 1) << 6;
      #pragma unroll
      for (int i = 0; i < 4; i++){
        int c = w * 4 + i;
        int row = c * 8 + r8;
        gload_lds16(Ap + (size_t)row * K + k0n, &As[cur ^ 1][c * 512]);
        gload_lds16(Bp + (size_t)row * K + k0n, &Bs[cur ^ 1][c * 512]);
      }
    }
    bf16x8 af[4][2], bfr[4][2];
    #pragma unroll
    for (int mi = 0; mi < 4; mi++){
      int row = wr + mi * 16 + l16;
      #pragma unroll
      for (int s = 0; s < 2; s++){
        int k = s * 32 + lhi * 8;
        int off = row * 128 + ((k * 2) ^ ((row & 7) << 4));
        af[mi][s] = *(const bf16x8*)((const char*)As[cur] + off);
      }
    }
    #pragma unroll
    for (int ni = 0; ni < 4; ni++){
      int row = wc + ni * 16 + l16;
      #pragma unroll
      for (int s = 0; s < 2; s++){
        int k = s * 32 + lhi * 8;
        int off = row * 128 + ((k * 2) ^ ((row & 7) << 4));
        bfr[ni][s] = *(const bf16x8*)((const char*)Bs[cur] + off);
      }
    }
    #pragma unroll
    for (int mi = 0; mi < 4; mi++)
      #pragma unroll
      for (int ni = 0; ni < 4; ni++){
        acc[mi][ni] = __builtin_amdgcn_mfma_f32_16x16x32_bf16(af[mi][0], bfr[ni][0], acc[mi][ni], 0, 0, 0);
        acc[mi][ni] = __builtin_amdgcn_mfma_f32_16x16x32_bf16(af[mi][1], bfr[ni][1], acc[mi][ni], 0, 0, 0);
      }
    __syncthreads();
    cur ^= 1;
  }

  unsigned short* C = isW ? HB : RB;
  #pragma unroll
  for (int mi = 0; mi < 4; mi++){
    #pragma unroll
    for (int j = 0; j < 4; j++){
      int r = rowA + wr + mi * 16 + lhi * 4 + j;
      unsigned short* Cp = C + (size_t)r * NN + colB + wc + l16;
      #pragma unroll
      for (int ni = 0; ni < 4; ni++)
        Cp[ni * 16] = f2bf(acc[mi][ni][j]);
    }
  }
}

// ---------------- attention: one wave per destination node; RB(bf16) += attn ----------------
template<int D>
__global__ __launch_bounds__(256) void k_attn(const unsigned short* __restrict__ HB,
                                              unsigned short* __restrict__ RB,
                                              const float* __restrict__ el,
                                              const float* __restrict__ er,
                                              const int* __restrict__ rowptr,
                                              const int* __restrict__ perm){
  constexpr int ITER = (2*D)/256;
  int wid = threadIdx.x >> 6, lane = threadIdx.x & 63;
  int nb = (blockIdx.x & 7) * (NNODES/4/8) + (blockIdx.x >> 3);   // bijective: 4096 = 8*512
  int n = nb * 4 + wid;
  int r0 = rowptr[n], r1 = rowptr[n+1];
  if (r0 == r1) return;   // no in-edges: output = residual already in RB
  float er0 = er[n*2], er1 = er[n*2+1];
  float mx0 = -1e30f, mx1 = -1e30f;
  for (int e = r0 + lane; e < r1; e += 64){
    int s = perm[e];
    mx0 = fmaxf(mx0, leaky(el[s*2]   + er0, 0.2f));
    mx1 = fmaxf(mx1, leaky(el[s*2+1] + er1, 0.2f));
  }
  #pragma unroll
  for (int o = 32; o; o >>= 1){ mx0 = fmaxf(mx0, __shfl_xor(mx0, o)); mx1 = fmaxf(mx1, __shfl_xor(mx1, o)); }
  float sm0 = 0.0f, sm1 = 0.0f;
  for (int e = r0 + lane; e < r1; e += 64){
    int s = perm[e];
    sm0 += expf(leaky(el[s*2]   + er0, 0.2f) - mx0);
    sm1 += expf(leaky(el[s*2+1] + er1, 0.2f) - mx1);
  }
  #pragma unroll
  for (int o = 32; o; o >>= 1){ sm0 += __shfl_xor(sm0, o); sm1 += __shfl_xor(sm1, o); }
  float inv0 = 1.0f / sm0, inv1 = 1.0f / sm1;
  float acc[ITER][4];
  #pragma unroll
  for (int j = 0; j < ITER; j++)
    #pragma unroll
    for (int i = 0; i < 4; i++) acc[j][i] = 0.0f;
  for (int e = r0; e < r1; ++e){
    int s = perm[e];
    float a0 = expf(leaky(el[s*2]   + er0, 0.2f) - mx0) * inv0;
    float a1 = expf(leaky(el[s*2+1] + er1, 0.2f) - mx1) * inv1;
    const unsigned short* hrow = HB + (size_t)s * (2*D);
    #pragma unroll
    for (int j = 0; j < ITER; j++){
      int base = j*256 + lane*4;
      bf16x4 v = *(const bf16x4*)(hrow + base);
      float a = (base < D) ? a0 : a1;
      #pragma unroll
      for (int i = 0; i < 4; i++)
        acc[j][i] += a * bf2f((unsigned short)v[i]);
    }
  }
  unsigned short* rrow = RB + (size_t)n * (2*D);
  #pragma unroll
  for (int j = 0; j < ITER; j++){
    int base = j*256 + lane*4;
    bf16x4 r = *(bf16x4*)(rrow + base);
    ushort4 o;
    o.x = f2bf(bf2f((unsigned short)r[0]) + acc[j][0]);
    o.y = f2bf(bf2f((unsigned short)r[1]) + acc[j][1]);
    o.z = f2bf(bf2f((unsigned short)r[2]) + acc[j][2]);
    o.w = f2bf(bf2f((unsigned short)r[3]) + acc[j][3]);
    *(ushort4*)(rrow + base) = o;
  }
}

// ------- GraphNorm stats (bf16 in): grid (NNODES/128, nn/256); lane owns 4 cols -------
__global__ __launch_bounds__(256) void k_stats(const unsigned short* __restrict__ R, int nn,
                                               float* __restrict__ gsum, float* __restrict__ gsq){
  int t = threadIdx.x, lane = t & 63, w = t >> 6;
  int c = blockIdx.y * 256 + lane * 4;
  const unsigned short* base = R + (size_t)(blockIdx.x * 128 + w) * nn + c;
  float4 s = make_float4(0,0,0,0), q = make_float4(0,0,0,0);
  #pragma unroll 4
  for (int i = 0; i < 32; i++){
    bf16x4 bv = *(const bf16x4*)(base + (size_t)(i * 4) * nn);
    float vx = bf2f((unsigned short)bv[0]), vy = bf2f((unsigned short)bv[1]);
    float vz = bf2f((unsigned short)bv[2]), vw = bf2f((unsigned short)bv[3]);
    s.x += vx; s.y += vy; s.z += vz; s.w += vw;
    q.x += vx*vx; q.y += vy*vy; q.z += vz*vz; q.w += vw*vw;
  }
  __shared__ float4 rs[256], rq[256];
  rs[t] = s; rq[t] = q; __syncthreads();
  if (t < 64){
    float4 a = rs[t], b = rs[t+64], c2 = rs[t+128], d2 = rs[t+192];
    float4 e = rq[t], f = rq[t+64], g2 = rq[t+128], h2 = rq[t+192];
    int cc = blockIdx.y * 256 + t * 4;
    atomicAdd(&gsum[cc+0], a.x+b.x+c2.x+d2.x);
    atomicAdd(&gsum[cc+1], a.y+b.y+c2.y+d2.y);
    atomicAdd(&gsum[cc+2], a.z+b.z+c2.z+d2.z);
    atomicAdd(&gsum[cc+3], a.w+b.w+c2.w+d2.w);
    atomicAdd(&gsq [cc+0], e.x+f.x+g2.x+h2.x);
    atomicAdd(&gsq [cc+1], e.y+f.y+g2.y+h2.y);
    atomicAdd(&gsq [cc+2], e.z+f.z+g2.z+h2.z);
    atomicAdd(&gsq [cc+3], e.w+f.w+g2.w+h2.w);
  }
}

// -- norm apply + leaky + head-mean pool (bf16 in) with INLINE stats finalize --
// grid (NNODES/128, nn/256); params are d-length; column c -> channel c & (d-1).
__global__ __launch_bounds__(256) void k_norm_pool(const unsigned short* __restrict__ R,
                                                   unsigned short* __restrict__ Xn, // bf16 next-layer input (or null)
                                                   const float* __restrict__ gsum,
                                                   const float* __restrict__ gsq,
                                                   const float* __restrict__ gamma,
                                                   const float* __restrict__ beta,
                                                   const float* __restrict__ alpha,
                                                   float* __restrict__ pool, int d, int loff){
  int t = threadIdx.x, lane = t & 63, w = t >> 6;
  int c = blockIdx.y * 256 + lane * 4;
  int cm = c & (d - 1);                    // channel index (d-periodic), 4-aligned
  int nodeb = blockIdx.x * 128;
  int g = blockIdx.x >> 3;                 // 8 row-blocks per graph (1024 nodes/graph)
  int nn = 2 * d;
  const float Minv = 1.0f / (2.0f * (float)NNODES);
  float4 gg = *(const float4*)(gamma + cm);
  float4 bb = *(const float4*)(beta + cm);
  float4 aa = *(const float4*)(alpha + cm);
  float mmv[4], rrv[4];
  #pragma unroll
  for (int i = 0; i < 4; i++){
    float m = (gsum[cm+i] + gsum[cm+i+d]) * Minv;
    float q = (gsq [cm+i] + gsq [cm+i+d]) * Minv;
    float a = (i==0)?aa.x:(i==1)?aa.y:(i==2)?aa.z:aa.w;
    float var = q - a * m * m * (2.0f - a);
    mmv[i] = m; rrv[i] = rsqrtf(var + 1e-5f);
  }
  float am0 = aa.x*mmv[0], am1 = aa.y*mmv[1], am2 = aa.z*mmv[2], am3 = aa.w*mmv[3];
  const unsigned short* base = R + (size_t)(nodeb + w) * nn + c;
  unsigned short* xb = Xn ? (Xn + (size_t)(nodeb + w) * nn + c) : nullptr;
  float4 accp = make_float4(0,0,0,0);
  #pragma unroll 4
  for (int i = 0; i < 32; i++){
    bf16x4 bv = *(const bf16x4*)(base + (size_t)(i * 4) * nn);
    float vx = bf2f((unsigned short)bv[0]), vy = bf2f((unsigned short)bv[1]);
    float vz = bf2f((unsigned short)bv[2]), vw = bf2f((unsigned short)bv[3]);
    float y0 = gg.x*(vx-am0)*rrv[0] + bb.x; y0 = y0 >= 0.f ? y0 : 0.01f*y0;
    float y1 = gg.y*(vy-am1)*rrv[1] + bb.y; y1 = y1 >= 0.f ? y1 : 0.01f*y1;
    float y2 = gg.z*(vz-am2)*rrv[2] + bb.z; y2 = y2 >= 0.f ? y2 : 0.01f*y2;
    float y3 = gg.w*(vw-am3)*rrv[3] + bb.w; y3 = y3 >= 0.f ? y3 : 0.01f*y3;
    if (xb){
      ushort4 o; o.x = f2bf(y0); o.y = f2bf(y1); o.z = f2bf(y2); o.w = f2bf(y3);
      *(ushort4*)(xb + (size_t)(i * 4) * nn) = o;
    }
    accp.x += y0; accp.y += y1; accp.z += y2; accp.w += y3;
  }
  __shared__ float4 red[256];
  red[t] = accp; __syncthreads();
  if (t < 64){
    float4 a = red[t], b = red[t+64], c2 = red[t+128], d2 = red[t+192];
    int cc = blockIdx.y * 256 + t * 4;
    float* pb = pool + g * 896 + loff;
    atomicAdd(&pb[(cc+0) & (d-1)], 0.5f*(a.x+b.x+c2.x+d2.x));
    atomicAdd(&pb[(cc+1) & (d-1)], 0.5f*(a.y+b.y+c2.y+d2.y));
    atomicAdd(&pb[(cc+2) & (d-1)], 0.5f*(a.z+b.z+c2.z+d2.z));
    atomicAdd(&pb[(cc+3) & (d-1)], 0.5f*(a.w+b.w+c2.w+d2.w));
  }
}

__global__ void k_final(const float* __restrict__ pool, const float* __restrict__ counts,
                        float* __restrict__ out){
  int idx = blockIdx.x * 256 + threadIdx.x;
  if (idx >= NGRAPHS * 896) return;
  int g = idx / 896;
  float v = pool[idx] / counts[g];
  out[idx] = v >= 0.0f ? v : 0.01f * v;
}

// ---------------------------------------------------------------------------------------
extern "C" void kernel_launch(void* const* d_in, const int* in_sizes, int n_in,
                              void* d_out, int out_size, void* d_ws, size_t ws_size,
                              hipStream_t stream){
  const float* x0 = (const float*)d_in[0];
  const float *W[3], *AL[3], *AR[3], *RW[3], *GA[3], *BE[3], *ALP[3];
  for (int l = 0; l < 3; l++){
    const int b = 1 + l*7;
    W[l]  = (const float*)d_in[b+0];
    AL[l] = (const float*)d_in[b+1];
    AR[l] = (const float*)d_in[b+2];
    RW[l] = (const float*)d_in[b+3];
    GA[l] = (const float*)d_in[b+4];
    BE[l] = (const float*)d_in[b+5];
    ALP[l]= (const float*)d_in[b+6];
  }
  const int* esrc = (const int*)d_in[22];
  const int* edst = (const int*)d_in[23];
  const int* gid  = (const int*)d_in[24];
  float* out = (float*)d_out;

  char* p = (char*)d_ws;
  auto carve = [&](size_t bytes)->void*{
    void* r = (void*)p; p += (bytes + 255) & ~(size_t)255; return r;
  };
  unsigned short* HB = (unsigned short*)carve((size_t)NNODES * 1024 * 2);  // h bf16 [N, 2d]
  unsigned short* RB = (unsigned short*)carve((size_t)NNODES * 1024 * 2);  // r/out bf16 [N, 2d]
  unsigned short* X0b = (unsigned short*)carve((size_t)NNODES * 128 * 2);  // bf16 layer-0 input
  unsigned short* XA  = (unsigned short*)carve((size_t)NNODES * 256 * 2);  // bf16 y0
  unsigned short* XB  = (unsigned short*)carve((size_t)NNODES * 512 * 2);  // bf16 y1
  unsigned short* Wt  = (unsigned short*)carve((size_t)1024 * 512 * 2);    // bf16 W^T (max)
  unsigned short* RWt = (unsigned short*)carve((size_t)1024 * 512 * 2);    // bf16 resW^T (max)
  float* el     = (float*)carve((size_t)NNODES * 2 * 4);
  float* er     = (float*)carve((size_t)NNODES * 2 * 4);
  float* Wal    = (float*)carve((size_t)512 * 4 * 4);        // [K][4] el/er projection
  int*   deg    = (int*)  carve((size_t)NNODES * 4);
  int*   rowptr = (int*)  carve((size_t)(NNODES + 1) * 4);
  int*   cursor = (int*)  carve((size_t)NNODES * 4);
  int*   perm   = (int*)  carve((size_t)NEDGES * 4);
  float* stats  = (float*)carve(2048 * 4);                   // gsum[1024] | gsq[1024]
  float* pool   = (float*)carve((size_t)NGRAPHS * 896 * 4);
  float* countsF= (float*)carve((size_t)NGRAPHS * 4);
  (void)ws_size; (void)in_sizes; (void)n_in; (void)out_size;

  hipMemsetAsync(deg, 0, NNODES * 4, stream);
  hipMemsetAsync(pool, 0, NGRAPHS * 896 * 4, stream);
  hipMemsetAsync(countsF, 0, NGRAPHS * 4, stream);

  k_deg    <<<NEDGES/256, 256, 0, stream>>>(edst, deg);
  k_scan   <<<1, 1024, 0, stream>>>(deg, rowptr, cursor);
  k_scatter<<<NEDGES/256, 256, 0, stream>>>(esrc, edst, cursor, perm);
  k_counts <<<NNODES/1024, 256, 0, stream>>>(gid, countsF);
  k_cvt    <<<(NNODES*128/4 + 255)/256, 256, 0, stream>>>(x0, X0b, NNODES*128/4);

  const unsigned short* xin = X0b;
  int loff = 0;
  const int dims[3] = {128, 256, 512};
  for (int l = 0; l < 3; l++){
    int d = dims[l], nn = 2*d;
    dim3 gt(nn/32, d/32, 2);
    k_cvt_t2<<<gt, 256, 0, stream>>>(W[l], RW[l], Wt, RWt, d, nn);
    k_wal   <<<(d+3)/4, 256, 0, stream>>>(W[l], AL[l], AR[l], Wal, d, nn);
    k_elxw  <<<NNODES/4, 256, 0, stream>>>(xin, Wal, el, er, d);
    dim3 gg(2*nn/128, NNODES/128);
    k_gemm2<<<gg, 256, 0, stream>>>(xin, Wt, RWt, HB, RB, d, nn);
    if (d == 128){
      k_attn<128><<<NNODES/4, 256, 0, stream>>>(HB, RB, el, er, rowptr, perm);
    } else if (d == 256){
      k_attn<256><<<NNODES/4, 256, 0, stream>>>(HB, RB, el, er, rowptr, perm);
    } else {
      k_attn<512><<<NNODES/4, 256, 0, stream>>>(HB, RB, el, er, rowptr, perm);
    }
    hipMemsetAsync(stats, 0, 2048 * 4, stream);
    dim3 gs(NNODES/128, nn/256);
    k_stats   <<<gs, 256, 0, stream>>>(RB, nn, stats, stats + 1024);
    unsigned short* xn = (l == 0) ? XA : (l == 1) ? XB : nullptr;
    k_norm_pool<<<gs, 256, 0, stream>>>(RB, xn, stats, stats + 1024, GA[l], BE[l], ALP[l], pool, d, loff);
    xin = xn; loff += d;
  }
  k_final<<<(NGRAPHS*896 + 255)/256, 256, 0, stream>>>(pool, countsF, out);
}

// Round 15
// 343.016 us; speedup vs baseline: 1.1126x; 1.0362x over previous
//
#include <hip/hip_runtime.h>
#include <math.h>

constexpr int NNODES  = 16384;
constexpr int NEDGES  = 131072;
constexpr int NGRAPHS = 16;

typedef short bf16x8 __attribute__((ext_vector_type(8)));
typedef short bf16x4 __attribute__((ext_vector_type(4)));
typedef float f32x4  __attribute__((ext_vector_type(4)));

__device__ __forceinline__ float leaky(float x, float s){ return x >= 0.0f ? x : s * x; }

__device__ __forceinline__ unsigned short f2bf(float f){
  unsigned u = __builtin_bit_cast(unsigned, f);
  u += 0x7FFFu + ((u >> 16) & 1u);          // round-to-nearest-even
  return (unsigned short)(u >> 16);
}
__device__ __forceinline__ float bf2f(unsigned short u){
  unsigned x = (unsigned)u << 16; return __builtin_bit_cast(float, x);
}

__device__ __forceinline__ void gload_lds16(const unsigned short* g, unsigned short* l){
  __builtin_amdgcn_global_load_lds((const __attribute__((address_space(1))) void*)g,
                                   (__attribute__((address_space(3))) void*)l, 16, 0, 0);
}

// ---------------- CSR build (edges fixed across layers; build once) ----------------
__global__ void k_deg(const int* __restrict__ dst, int* __restrict__ deg){
  int e = blockIdx.x * 256 + threadIdx.x;
  if (e < NEDGES) atomicAdd(&deg[dst[e]], 1);
}

__global__ __launch_bounds__(1024) void k_scan(const int* __restrict__ deg,
                                               int* __restrict__ rowptr,
                                               int* __restrict__ cursor){
  __shared__ int sums[1024];
  int t = threadIdx.x;
  int loc[16];
  int s = 0;
  #pragma unroll
  for (int i = 0; i < 16; i++){ loc[i] = deg[t*16 + i]; s += loc[i]; }
  sums[t] = s; __syncthreads();
  for (int off = 1; off < 1024; off <<= 1){
    int v = (t >= off) ? sums[t - off] : 0;
    __syncthreads();
    sums[t] += v;
    __syncthreads();
  }
  int base = (t > 0) ? sums[t-1] : 0;
  #pragma unroll
  for (int i = 0; i < 16; i++){
    rowptr[t*16 + i] = base; cursor[t*16 + i] = base; base += loc[i];
  }
  if (t == 1023) rowptr[NNODES] = base;
}

__global__ void k_scatter(const int* __restrict__ src, const int* __restrict__ dst,
                          int* __restrict__ cursor, int* __restrict__ perm){
  int e = blockIdx.x * 256 + threadIdx.x;
  if (e < NEDGES){ int p = atomicAdd(&cursor[dst[e]], 1); perm[p] = src[e]; }
}

// ---- graph-size counts: LDS histogram per block, one global atomic per (block,graph) ----
__global__ __launch_bounds__(256) void k_counts(const int* __restrict__ gid, float* __restrict__ counts){
  __shared__ int h[NGRAPHS];
  int t = threadIdx.x;
  if (t < NGRAPHS) h[t] = 0;
  __syncthreads();
  int base = blockIdx.x * 1024;
  #pragma unroll
  for (int i = 0; i < 4; i++)
    atomicAdd(&h[gid[base + t + i*256]], 1);
  __syncthreads();
  if (t < NGRAPHS && h[t] > 0) atomicAdd(&counts[t], (float)h[t]);
}

// ---------------- fp32 -> bf16 convert (contiguous) ----------------
__global__ void k_cvt(const float* __restrict__ in, unsigned short* __restrict__ out, int n4){
  int i = blockIdx.x * 256 + threadIdx.x;
  if (i >= n4) return;
  float4 v = ((const float4*)in)[i];
  ushort4 o; o.x = f2bf(v.x); o.y = f2bf(v.y); o.z = f2bf(v.z); o.w = f2bf(v.w);
  ((ushort4*)out)[i] = o;
}

// -------- fp32 [K][NN] -> bf16 transposed [NN][K], both W and RW in one launch --------
__global__ __launch_bounds__(256) void k_cvt_t2(const float* __restrict__ W,
                                                const float* __restrict__ RW,
                                                unsigned short* __restrict__ Wt,
                                                unsigned short* __restrict__ RWt,
                                                int K, int NN){
  __shared__ float tile[32][33];
  const float* src = blockIdx.z ? RW : W;
  unsigned short* dst = blockIdx.z ? RWt : Wt;
  int n0 = blockIdx.x * 32, k0 = blockIdx.y * 32;
  int tx = threadIdx.x & 31, ty = threadIdx.x >> 5;   // 32 x 8
  #pragma unroll
  for (int i = 0; i < 4; i++)
    tile[ty + i*8][tx] = src[(size_t)(k0 + ty + i*8) * NN + n0 + tx];
  __syncthreads();
  #pragma unroll
  for (int i = 0; i < 4; i++)
    dst[(size_t)(n0 + ty + i*8) * K + k0 + tx] = f2bf(tile[tx][ty + i*8]);
}

// ------- shared-A triple-tile bf16 MFMA GEMM: H = A@Wt^T, R = A@RWt^T -------
// Block = 128 rows x 64 cols for BOTH matrices; A staged once, reused by W and R
// panels. 256 threads / 4 waves, per-wave 64x32 per matrix (acc 64 regs total).
// 32 KB LDS, single-buffered m97 2-barrier loop. Pre-swizzled global source,
// XOR-swizzled ds_read, XCD-aware bijective swizzle.
// W epilogue: el/er partial dots over this wave's 32 cols -> elp/erp (G = NN/32).
__global__ __launch_bounds__(256) void k_gemm2(const unsigned short* __restrict__ A,
                                               const unsigned short* __restrict__ Wt,
                                               const unsigned short* __restrict__ RWt,
                                               unsigned short* __restrict__ HB,
                                               unsigned short* __restrict__ RB,
                                               const float* __restrict__ al,
                                               const float* __restrict__ ar,
                                               float* __restrict__ elp,
                                               float* __restrict__ erp,
                                               int K, int NN){
  __shared__ unsigned short As[128 * 64];   // 16 KB
  __shared__ unsigned short Ws[64 * 64];    // 8 KB
  __shared__ unsigned short Rs[64 * 64];    // 8 KB
  int t = threadIdx.x;
  int lane = t & 63, w = t >> 6;
  int nx  = gridDim.x;                       // NN/64
  int nwg = nx * gridDim.y;                  // multiple of 8
  int bid = blockIdx.x + blockIdx.y * nx;
  int wg  = (bid & 7) * (nwg >> 3) + (bid >> 3);
  int bx = wg % nx, by = wg / nx;
  int colB = bx * 64;
  int rowA = by * 128;

  int wr = (w >> 1) * 64, wc = (w & 1) * 32;   // wave: 64 rows x 32 cols
  int l16 = lane & 15, lhi = lane >> 4;
  int r8  = lane >> 3;
  int kcs = (((lane & 7) * 16) ^ (r8 << 4)) >> 1;   // shorts, lane-constant

  f32x4 accW[4][2] = {};
  f32x4 accR[4][2] = {};

  const unsigned short* Ap = A   + (size_t)rowA * K + kcs;
  const unsigned short* Wp = Wt  + (size_t)colB * K + kcs;
  const unsigned short* Rp = RWt + (size_t)colB * K + kcs;

  for (int k0 = 0; k0 < K; k0 += 64){
    __syncthreads();   // previous step's LDS reads done
    // stage A (16 chunks of 8 rows), W (8 chunks), R (8 chunks)
    #pragma unroll
    for (int i = 0; i < 4; i++){
      int c = w * 4 + i;
      gload_lds16(Ap + (size_t)(c * 8 + r8) * K + k0, &As[c * 512]);
    }
    #pragma unroll
    for (int i = 0; i < 2; i++){
      int c = w * 2 + i;
      size_t go = (size_t)(c * 8 + r8) * K + k0;
      gload_lds16(Wp + go, &Ws[c * 512]);
      gload_lds16(Rp + go, &Rs[c * 512]);
    }
    __syncthreads();   // implicit vmcnt(0) drain: tiles ready
    #pragma unroll
    for (int s = 0; s < 2; s++){
      int k = s * 32 + lhi * 8;
      bf16x8 af[4], bw[2], br[2];
      #pragma unroll
      for (int mi = 0; mi < 4; mi++){
        int row = wr + mi * 16 + l16;
        int off = row * 128 + ((k * 2) ^ ((row & 7) << 4));
        af[mi] = *(const bf16x8*)((const char*)As + off);
      }
      #pragma unroll
      for (int ni = 0; ni < 2; ni++){
        int row = wc + ni * 16 + l16;
        int off = row * 128 + ((k * 2) ^ ((row & 7) << 4));
        bw[ni] = *(const bf16x8*)((const char*)Ws + off);
        br[ni] = *(const bf16x8*)((const char*)Rs + off);
      }
      #pragma unroll
      for (int mi = 0; mi < 4; mi++)
        #pragma unroll
        for (int ni = 0; ni < 2; ni++){
          accW[mi][ni] = __builtin_amdgcn_mfma_f32_16x16x32_bf16(af[mi], bw[ni], accW[mi][ni], 0, 0, 0);
          accR[mi][ni] = __builtin_amdgcn_mfma_f32_16x16x32_bf16(af[mi], br[ni], accR[mi][ni], 0, 0, 0);
        }
    }
  }

  #pragma unroll
  for (int mi = 0; mi < 4; mi++){
    #pragma unroll
    for (int j = 0; j < 4; j++){
      int r = rowA + wr + mi * 16 + lhi * 4 + j;
      unsigned short* Hp  = HB + (size_t)r * NN + colB + wc + l16;
      unsigned short* Rp2 = RB + (size_t)r * NN + colB + wc + l16;
      #pragma unroll
      for (int ni = 0; ni < 2; ni++){
        Hp[ni * 16]  = f2bf(accW[mi][ni][j]);
        Rp2[ni * 16] = f2bf(accR[mi][ni][j]);
      }
    }
  }

  // el/er partials over this wave's 32 columns (plain stores, no atomics)
  {
    int G = NN >> 5;
    int g32 = (colB + wc) >> 5;
    float alv0 = al[colB + wc + l16],      arv0 = ar[colB + wc + l16];
    float alv1 = al[colB + wc + 16 + l16], arv1 = ar[colB + wc + 16 + l16];
    #pragma unroll
    for (int mi = 0; mi < 4; mi++){
      #pragma unroll
      for (int j = 0; j < 4; j++){
        float pe = accW[mi][0][j]*alv0 + accW[mi][1][j]*alv1;
        float pr = accW[mi][0][j]*arv0 + accW[mi][1][j]*arv1;
        #pragma unroll
        for (int o = 8; o; o >>= 1){ pe += __shfl_xor(pe, o); pr += __shfl_xor(pr, o); }
        if (l16 == 0){
          int r = rowA + wr + mi * 16 + lhi * 4 + j;
          elp[(size_t)r * G + g32] = pe;
          erp[(size_t)r * G + g32] = pr;
        }
      }
    }
  }
}

// ---- reduce el/er partials: one thread per row; G = nn/32, half per head ----
__global__ void k_elred(const float* __restrict__ elp, const float* __restrict__ erp,
                        float* __restrict__ el, float* __restrict__ er, int G){
  int row = blockIdx.x * 256 + threadIdx.x;
  int half = G >> 1;
  float s0 = 0.f, s1 = 0.f, q0 = 0.f, q1 = 0.f;
  const float* ep = elp + (size_t)row * G;
  const float* rp = erp + (size_t)row * G;
  for (int i = 0; i < half; i++){ s0 += ep[i]; q0 += rp[i]; }
  for (int i = half; i < G; i++){ s1 += ep[i]; q1 += rp[i]; }
  el[row*2] = s0; el[row*2+1] = s1;
  er[row*2] = q0; er[row*2+1] = q1;
}

// ---------------- attention: one wave per destination node; RB(bf16) += attn ----------------
template<int D>
__global__ __launch_bounds__(256) void k_attn(const unsigned short* __restrict__ HB,
                                              unsigned short* __restrict__ RB,
                                              const float* __restrict__ el,
                                              const float* __restrict__ er,
                                              const int* __restrict__ rowptr,
                                              const int* __restrict__ perm){
  constexpr int ITER = (2*D)/256;
  int wid = threadIdx.x >> 6, lane = threadIdx.x & 63;
  int nb = (blockIdx.x & 7) * (NNODES/4/8) + (blockIdx.x >> 3);   // bijective: 4096 = 8*512
  int n = nb * 4 + wid;
  int r0 = rowptr[n], r1 = rowptr[n+1];
  if (r0 == r1) return;   // no in-edges: output = residual already in RB
  float er0 = er[n*2], er1 = er[n*2+1];
  float mx0 = -1e30f, mx1 = -1e30f;
  for (int e = r0 + lane; e < r1; e += 64){
    int s = perm[e];
    mx0 = fmaxf(mx0, leaky(el[s*2]   + er0, 0.2f));
    mx1 = fmaxf(mx1, leaky(el[s*2+1] + er1, 0.2f));
  }
  #pragma unroll
  for (int o = 32; o; o >>= 1){ mx0 = fmaxf(mx0, __shfl_xor(mx0, o)); mx1 = fmaxf(mx1, __shfl_xor(mx1, o)); }
  float sm0 = 0.0f, sm1 = 0.0f;
  for (int e = r0 + lane; e < r1; e += 64){
    int s = perm[e];
    sm0 += expf(leaky(el[s*2]   + er0, 0.2f) - mx0);
    sm1 += expf(leaky(el[s*2+1] + er1, 0.2f) - mx1);
  }
  #pragma unroll
  for (int o = 32; o; o >>= 1){ sm0 += __shfl_xor(sm0, o); sm1 += __shfl_xor(sm1, o); }
  float inv0 = 1.0f / sm0, inv1 = 1.0f / sm1;
  float acc[ITER][4];
  #pragma unroll
  for (int j = 0; j < ITER; j++)
    #pragma unroll
    for (int i = 0; i < 4; i++) acc[j][i] = 0.0f;
  for (int e = r0; e < r1; ++e){
    int s = perm[e];
    float a0 = expf(leaky(el[s*2]   + er0, 0.2f) - mx0) * inv0;
    float a1 = expf(leaky(el[s*2+1] + er1, 0.2f) - mx1) * inv1;
    const unsigned short* hrow = HB + (size_t)s * (2*D);
    #pragma unroll
    for (int j = 0; j < ITER; j++){
      int base = j*256 + lane*4;
      bf16x4 v = *(const bf16x4*)(hrow + base);
      float a = (base < D) ? a0 : a1;
      #pragma unroll
      for (int i = 0; i < 4; i++)
        acc[j][i] += a * bf2f((unsigned short)v[i]);
    }
  }
  unsigned short* rrow = RB + (size_t)n * (2*D);
  #pragma unroll
  for (int j = 0; j < ITER; j++){
    int base = j*256 + lane*4;
    bf16x4 r = *(bf16x4*)(rrow + base);
    ushort4 o;
    o.x = f2bf(bf2f((unsigned short)r[0]) + acc[j][0]);
    o.y = f2bf(bf2f((unsigned short)r[1]) + acc[j][1]);
    o.z = f2bf(bf2f((unsigned short)r[2]) + acc[j][2]);
    o.w = f2bf(bf2f((unsigned short)r[3]) + acc[j][3]);
    *(ushort4*)(rrow + base) = o;
  }
}

// ------- GraphNorm stats (bf16 in): grid (NNODES/128, nn/256); lane owns 4 cols -------
__global__ __launch_bounds__(256) void k_stats(const unsigned short* __restrict__ R, int nn,
                                               float* __restrict__ gsum, float* __restrict__ gsq){
  int t = threadIdx.x, lane = t & 63, w = t >> 6;
  int c = blockIdx.y * 256 + lane * 4;
  const unsigned short* base = R + (size_t)(blockIdx.x * 128 + w) * nn + c;
  float4 s = make_float4(0,0,0,0), q = make_float4(0,0,0,0);
  #pragma unroll 4
  for (int i = 0; i < 32; i++){
    bf16x4 bv = *(const bf16x4*)(base + (size_t)(i * 4) * nn);
    float vx = bf2f((unsigned short)bv[0]), vy = bf2f((unsigned short)bv[1]);
    float vz = bf2f((unsigned short)bv[2]), vw = bf2f((unsigned short)bv[3]);
    s.x += vx; s.y += vy; s.z += vz; s.w += vw;
    q.x += vx*vx; q.y += vy*vy; q.z += vz*vz; q.w += vw*vw;
  }
  __shared__ float4 rs[256], rq[256];
  rs[t] = s; rq[t] = q; __syncthreads();
  if (t < 64){
    float4 a = rs[t], b = rs[t+64], c2 = rs[t+128], d2 = rs[t+192];
    float4 e = rq[t], f = rq[t+64], g2 = rq[t+128], h2 = rq[t+192];
    int cc = blockIdx.y * 256 + t * 4;
    atomicAdd(&gsum[cc+0], a.x+b.x+c2.x+d2.x);
    atomicAdd(&gsum[cc+1], a.y+b.y+c2.y+d2.y);
    atomicAdd(&gsum[cc+2], a.z+b.z+c2.z+d2.z);
    atomicAdd(&gsum[cc+3], a.w+b.w+c2.w+d2.w);
    atomicAdd(&gsq [cc+0], e.x+f.x+g2.x+h2.x);
    atomicAdd(&gsq [cc+1], e.y+f.y+g2.y+h2.y);
    atomicAdd(&gsq [cc+2], e.z+f.z+g2.z+h2.z);
    atomicAdd(&gsq [cc+3], e.w+f.w+g2.w+h2.w);
  }
}

// -- norm apply + leaky + head-mean pool (bf16 in) with INLINE stats finalize --
// grid (NNODES/128, nn/256); params are d-length; column c -> channel c & (d-1).
__global__ __launch_bounds__(256) void k_norm_pool(const unsigned short* __restrict__ R,
                                                   unsigned short* __restrict__ Xn, // bf16 next-layer input (or null)
                                                   const float* __restrict__ gsum,
                                                   const float* __restrict__ gsq,
                                                   const float* __restrict__ gamma,
                                                   const float* __restrict__ beta,
                                                   const float* __restrict__ alpha,
                                                   float* __restrict__ pool, int d, int loff){
  int t = threadIdx.x, lane = t & 63, w = t >> 6;
  int c = blockIdx.y * 256 + lane * 4;
  int cm = c & (d - 1);                    // channel index (d-periodic), 4-aligned
  int nodeb = blockIdx.x * 128;
  int g = blockIdx.x >> 3;                 // 8 row-blocks per graph (1024 nodes/graph)
  int nn = 2 * d;
  const float Minv = 1.0f / (2.0f * (float)NNODES);
  float4 gg = *(const float4*)(gamma + cm);
  float4 bb = *(const float4*)(beta + cm);
  float4 aa = *(const float4*)(alpha + cm);
  float mmv[4], rrv[4];
  #pragma unroll
  for (int i = 0; i < 4; i++){
    float m = (gsum[cm+i] + gsum[cm+i+d]) * Minv;
    float q = (gsq [cm+i] + gsq [cm+i+d]) * Minv;
    float a = (i==0)?aa.x:(i==1)?aa.y:(i==2)?aa.z:aa.w;
    float var = q - a * m * m * (2.0f - a);
    mmv[i] = m; rrv[i] = rsqrtf(var + 1e-5f);
  }
  float am0 = aa.x*mmv[0], am1 = aa.y*mmv[1], am2 = aa.z*mmv[2], am3 = aa.w*mmv[3];
  const unsigned short* base = R + (size_t)(nodeb + w) * nn + c;
  unsigned short* xb = Xn ? (Xn + (size_t)(nodeb + w) * nn + c) : nullptr;
  float4 accp = make_float4(0,0,0,0);
  #pragma unroll 4
  for (int i = 0; i < 32; i++){
    bf16x4 bv = *(const bf16x4*)(base + (size_t)(i * 4) * nn);
    float vx = bf2f((unsigned short)bv[0]), vy = bf2f((unsigned short)bv[1]);
    float vz = bf2f((unsigned short)bv[2]), vw = bf2f((unsigned short)bv[3]);
    float y0 = gg.x*(vx-am0)*rrv[0] + bb.x; y0 = y0 >= 0.f ? y0 : 0.01f*y0;
    float y1 = gg.y*(vy-am1)*rrv[1] + bb.y; y1 = y1 >= 0.f ? y1 : 0.01f*y1;
    float y2 = gg.z*(vz-am2)*rrv[2] + bb.z; y2 = y2 >= 0.f ? y2 : 0.01f*y2;
    float y3 = gg.w*(vw-am3)*rrv[3] + bb.w; y3 = y3 >= 0.f ? y3 : 0.01f*y3;
    if (xb){
      ushort4 o; o.x = f2bf(y0); o.y = f2bf(y1); o.z = f2bf(y2); o.w = f2bf(y3);
      *(ushort4*)(xb + (size_t)(i * 4) * nn) = o;
    }
    accp.x += y0; accp.y += y1; accp.z += y2; accp.w += y3;
  }
  __shared__ float4 red[256];
  red[t] = accp; __syncthreads();
  if (t < 64){
    float4 a = red[t], b = red[t+64], c2 = red[t+128], d2 = red[t+192];
    int cc = blockIdx.y * 256 + t * 4;
    float* pb = pool + g * 896 + loff;
    atomicAdd(&pb[(cc+0) & (d-1)], 0.5f*(a.x+b.x+c2.x+d2.x));
    atomicAdd(&pb[(cc+1) & (d-1)], 0.5f*(a.y+b.y+c2.y+d2.y));
    atomicAdd(&pb[(cc+2) & (d-1)], 0.5f*(a.z+b.z+c2.z+d2.z));
    atomicAdd(&pb[(cc+3) & (d-1)], 0.5f*(a.w+b.w+c2.w+d2.w));
  }
}

__global__ void k_final(const float* __restrict__ pool, const float* __restrict__ counts,
                        float* __restrict__ out){
  int idx = blockIdx.x * 256 + threadIdx.x;
  if (idx >= NGRAPHS * 896) return;
  int g = idx / 896;
  float v = pool[idx] / counts[g];
  out[idx] = v >= 0.0f ? v : 0.01f * v;
}

// ---------------------------------------------------------------------------------------
extern "C" void kernel_launch(void* const* d_in, const int* in_sizes, int n_in,
                              void* d_out, int out_size, void* d_ws, size_t ws_size,
                              hipStream_t stream){
  const float* x0 = (const float*)d_in[0];
  const float *W[3], *AL[3], *AR[3], *RW[3], *GA[3], *BE[3], *ALP[3];
  for (int l = 0; l < 3; l++){
    const int b = 1 + l*7;
    W[l]  = (const float*)d_in[b+0];
    AL[l] = (const float*)d_in[b+1];
    AR[l] = (const float*)d_in[b+2];
    RW[l] = (const float*)d_in[b+3];
    GA[l] = (const float*)d_in[b+4];
    BE[l] = (const float*)d_in[b+5];
    ALP[l]= (const float*)d_in[b+6];
  }
  const int* esrc = (const int*)d_in[22];
  const int* edst = (const int*)d_in[23];
  const int* gid  = (const int*)d_in[24];
  float* out = (float*)d_out;

  char* p = (char*)d_ws;
  auto carve = [&](size_t bytes)->void*{
    void* r = (void*)p; p += (bytes + 255) & ~(size_t)255; return r;
  };
  unsigned short* HB = (unsigned short*)carve((size_t)NNODES * 1024 * 2);  // h bf16 [N, 2d]
  unsigned short* RB = (unsigned short*)carve((size_t)NNODES * 1024 * 2);  // r/out bf16 [N, 2d]
  unsigned short* X0b = (unsigned short*)carve((size_t)NNODES * 128 * 2);  // bf16 layer-0 input
  unsigned short* XA  = (unsigned short*)carve((size_t)NNODES * 256 * 2);  // bf16 y0
  unsigned short* XB  = (unsigned short*)carve((size_t)NNODES * 512 * 2);  // bf16 y1
  unsigned short* Wt  = (unsigned short*)carve((size_t)1024 * 512 * 2);    // bf16 W^T (max)
  unsigned short* RWt = (unsigned short*)carve((size_t)1024 * 512 * 2);    // bf16 resW^T (max)
  float* el     = (float*)carve((size_t)NNODES * 2 * 4);
  float* er     = (float*)carve((size_t)NNODES * 2 * 4);
  float* elp    = (float*)carve((size_t)NNODES * 32 * 4);    // el partials (G<=32)
  float* erp    = (float*)carve((size_t)NNODES * 32 * 4);    // er partials
  int*   deg    = (int*)  carve((size_t)NNODES * 4);
  int*   rowptr = (int*)  carve((size_t)(NNODES + 1) * 4);
  int*   cursor = (int*)  carve((size_t)NNODES * 4);
  int*   perm   = (int*)  carve((size_t)NEDGES * 4);
  float* stats  = (float*)carve(2048 * 4);                   // gsum[1024] | gsq[1024]
  float* pool   = (float*)carve((size_t)NGRAPHS * 896 * 4);
  float* countsF= (float*)carve((size_t)NGRAPHS * 4);
  (void)ws_size; (void)in_sizes; (void)n_in; (void)out_size;

  hipMemsetAsync(deg, 0, NNODES * 4, stream);
  hipMemsetAsync(pool, 0, NGRAPHS * 896 * 4, stream);
  hipMemsetAsync(countsF, 0, NGRAPHS * 4, stream);

  k_deg    <<<NEDGES/256, 256, 0, stream>>>(edst, deg);
  k_scan   <<<1, 1024, 0, stream>>>(deg, rowptr, cursor);
  k_scatter<<<NEDGES/256, 256, 0, stream>>>(esrc, edst, cursor, perm);
  k_counts <<<NNODES/1024, 256, 0, stream>>>(gid, countsF);
  k_cvt    <<<(NNODES*128/4 + 255)/256, 256, 0, stream>>>(x0, X0b, NNODES*128/4);

  const unsigned short* xin = X0b;
  int loff = 0;
  const int dims[3] = {128, 256, 512};
  for (int l = 0; l < 3; l++){
    int d = dims[l], nn = 2*d;
    dim3 gt(nn/32, d/32, 2);
    k_cvt_t2<<<gt, 256, 0, stream>>>(W[l], RW[l], Wt, RWt, d, nn);
    dim3 gg(nn/64, NNODES/128);
    k_gemm2<<<gg, 256, 0, stream>>>(xin, Wt, RWt, HB, RB, AL[l], AR[l], elp, erp, d, nn);
    k_elred<<<NNODES/256, 256, 0, stream>>>(elp, erp, el, er, nn >> 5);
    if (d == 128){
      k_attn<128><<<NNODES/4, 256, 0, stream>>>(HB, RB, el, er, rowptr, perm);
    } else if (d == 256){
      k_attn<256><<<NNODES/4, 256, 0, stream>>>(HB, RB, el, er, rowptr, perm);
    } else {
      k_attn<512><<<NNODES/4, 256, 0, stream>>>(HB, RB, el, er, rowptr, perm);
    }
    hipMemsetAsync(stats, 0, 2048 * 4, stream);
    dim3 gs(NNODES/128, nn/256);
    k_stats   <<<gs, 256, 0, stream>>>(RB, nn, stats, stats + 1024);
    unsigned short* xn = (l == 0) ? XA : (l == 1) ? XB : nullptr;
    k_norm_pool<<<gs, 256, 0, stream>>>(RB, xn, stats, stats + 1024, GA[l], BE[l], ALP[l], pool, d, loff);
    xin = xn; loff += d;
  }
  k_final<<<(NGRAPHS*896 + 255)/256, 256, 0, stream>>>(pool, countsF, out);
}

// Round 16
// 338.931 us; speedup vs baseline: 1.1260x; 1.0121x over previous
//
#include <hip/hip_runtime.h>
#include <math.h>

constexpr int NNODES  = 16384;
constexpr int NEDGES  = 131072;
constexpr int NGRAPHS = 16;

typedef short bf16x8 __attribute__((ext_vector_type(8)));
typedef short bf16x4 __attribute__((ext_vector_type(4)));
typedef float f32x4  __attribute__((ext_vector_type(4)));

__device__ __forceinline__ float leaky(float x, float s){ return x >= 0.0f ? x : s * x; }

__device__ __forceinline__ unsigned short f2bf(float f){
  unsigned u = __builtin_bit_cast(unsigned, f);
  u += 0x7FFFu + ((u >> 16) & 1u);          // round-to-nearest-even
  return (unsigned short)(u >> 16);
}
__device__ __forceinline__ float bf2f(unsigned short u){
  unsigned x = (unsigned)u << 16; return __builtin_bit_cast(float, x);
}

__device__ __forceinline__ void gload_lds16(const unsigned short* g, unsigned short* l){
  __builtin_amdgcn_global_load_lds((const __attribute__((address_space(1))) void*)g,
                                   (__attribute__((address_space(3))) void*)l, 16, 0, 0);
}

// ---------------- CSR build (edges fixed across layers; build once) ----------------
__global__ void k_deg(const int* __restrict__ dst, int* __restrict__ deg){
  int e = blockIdx.x * 256 + threadIdx.x;
  if (e < NEDGES) atomicAdd(&deg[dst[e]], 1);
}

__global__ __launch_bounds__(1024) void k_scan(const int* __restrict__ deg,
                                               int* __restrict__ rowptr,
                                               int* __restrict__ cursor){
  __shared__ int sums[1024];
  int t = threadIdx.x;
  int loc[16];
  int s = 0;
  #pragma unroll
  for (int i = 0; i < 16; i++){ loc[i] = deg[t*16 + i]; s += loc[i]; }
  sums[t] = s; __syncthreads();
  for (int off = 1; off < 1024; off <<= 1){
    int v = (t >= off) ? sums[t - off] : 0;
    __syncthreads();
    sums[t] += v;
    __syncthreads();
  }
  int base = (t > 0) ? sums[t-1] : 0;
  #pragma unroll
  for (int i = 0; i < 16; i++){
    rowptr[t*16 + i] = base; cursor[t*16 + i] = base; base += loc[i];
  }
  if (t == 1023) rowptr[NNODES] = base;
}

__global__ void k_scatter(const int* __restrict__ src, const int* __restrict__ dst,
                          int* __restrict__ cursor, int* __restrict__ perm){
  int e = blockIdx.x * 256 + threadIdx.x;
  if (e < NEDGES){ int p = atomicAdd(&cursor[dst[e]], 1); perm[p] = src[e]; }
}

// ---- graph-size counts: LDS histogram per block, one global atomic per (block,graph) ----
__global__ __launch_bounds__(256) void k_counts(const int* __restrict__ gid, float* __restrict__ counts){
  __shared__ int h[NGRAPHS];
  int t = threadIdx.x;
  if (t < NGRAPHS) h[t] = 0;
  __syncthreads();
  int base = blockIdx.x * 1024;
  #pragma unroll
  for (int i = 0; i < 4; i++)
    atomicAdd(&h[gid[base + t + i*256]], 1);
  __syncthreads();
  if (t < NGRAPHS && h[t] > 0) atomicAdd(&counts[t], (float)h[t]);
}

// ---------------- fp32 -> bf16 convert (contiguous) ----------------
__global__ void k_cvt(const float* __restrict__ in, unsigned short* __restrict__ out, int n4){
  int i = blockIdx.x * 256 + threadIdx.x;
  if (i >= n4) return;
  float4 v = ((const float4*)in)[i];
  ushort4 o; o.x = f2bf(v.x); o.y = f2bf(v.y); o.z = f2bf(v.z); o.w = f2bf(v.w);
  ((ushort4*)out)[i] = o;
}

// -------- fp32 [K][NN] -> bf16 transposed [NN][K], both W and RW in one launch --------
__global__ __launch_bounds__(256) void k_cvt_t2(const float* __restrict__ W,
                                                const float* __restrict__ RW,
                                                unsigned short* __restrict__ Wt,
                                                unsigned short* __restrict__ RWt,
                                                int K, int NN){
  __shared__ float tile[32][33];
  const float* src = blockIdx.z ? RW : W;
  unsigned short* dst = blockIdx.z ? RWt : Wt;
  int n0 = blockIdx.x * 32, k0 = blockIdx.y * 32;
  int tx = threadIdx.x & 31, ty = threadIdx.x >> 5;   // 32 x 8
  #pragma unroll
  for (int i = 0; i < 4; i++)
    tile[ty + i*8][tx] = src[(size_t)(k0 + ty + i*8) * NN + n0 + tx];
  __syncthreads();
  #pragma unroll
  for (int i = 0; i < 4; i++)
    dst[(size_t)(n0 + ty + i*8) * K + k0 + tx] = f2bf(tile[tx][ty + i*8]);
}

// ------- fused dual bf16 MFMA GEMM (R12 structure + counted-vmcnt pipeline) -------
// 128x128 tile, BK=64, double-buffered LDS. Per K-step: issue next-tile
// global_load_lds, then s_waitcnt vmcnt(8) (drains ONLY the oldest 8 = current
// tile; the 8 new loads stay in flight across the barrier) + raw s_barrier,
// then ds_read+MFMA, then a second plain s_barrier (reads consumed -> safe to
// overwrite next step). This removes the vmcnt(0) prefetch-drain that
// __syncthreads forced (the 2-phase's latency leak).
// W-half epilogue: per-64-col el/er partial dots -> elp/erp (plain stores).
__global__ __launch_bounds__(256) void k_gemm2(const unsigned short* __restrict__ A,
                                               const unsigned short* __restrict__ Wt,
                                               const unsigned short* __restrict__ RWt,
                                               unsigned short* __restrict__ HB,
                                               unsigned short* __restrict__ RB,
                                               const float* __restrict__ al,
                                               const float* __restrict__ ar,
                                               float* __restrict__ elp,
                                               float* __restrict__ erp,
                                               int K, int NN){
  __shared__ unsigned short As[2][128 * 64];
  __shared__ unsigned short Bs[2][128 * 64];
  int t = threadIdx.x;
  int lane = t & 63, w = t >> 6;
  int nx  = gridDim.x;                       // 2*NN/128
  int nwg = nx * gridDim.y;                  // multiple of 8
  int bid = blockIdx.x + blockIdx.y * nx;
  int wg  = (bid & 7) * (nwg >> 3) + (bid >> 3);
  int bx = wg % nx, by = wg / nx;
  int half = nx >> 1;
  bool isW = bx < half;
  const unsigned short* Bt = isW ? Wt : RWt;
  int colB = (isW ? bx : bx - half) * 128;
  int rowA = by * 128;

  int wr = (w >> 1) * 64, wc = (w & 1) * 64;
  int l16 = lane & 15, lhi = lane >> 4;
  int r8  = lane >> 3;
  int kcs = (((lane & 7) * 16) ^ (r8 << 4)) >> 1;   // shorts, lane-constant
  f32x4 acc[4][4] = {};

  const unsigned short* Ap = A  + (size_t)(rowA) * K + kcs;
  const unsigned short* Bp = Bt + (size_t)(colB) * K + kcs;

  int nt = K >> 6;
  // prologue: stage tile 0 into buf 0 (8 loads in flight; no drain yet)
  #pragma unroll
  for (int i = 0; i < 4; i++){
    int c = w * 4 + i;
    int row = c * 8 + r8;
    gload_lds16(Ap + (size_t)row * K, &As[0][c * 512]);
    gload_lds16(Bp + (size_t)row * K, &Bs[0][c * 512]);
  }

  int cur = 0;
  for (int tI = 0; tI < nt; tI++){
    if (tI + 1 < nt){
      int k0n = (tI + 1) << 6;
      #pragma unroll
      for (int i = 0; i < 4; i++){
        int c = w * 4 + i;
        int row = c * 8 + r8;
        gload_lds16(Ap + (size_t)row * K + k0n, &As[cur ^ 1][c * 512]);
        gload_lds16(Bp + (size_t)row * K + k0n, &Bs[cur ^ 1][c * 512]);
      }
      // outstanding = 16; wait until <=8 -> oldest 8 (tile tI) landed in LDS
      asm volatile("s_waitcnt vmcnt(8)" ::: "memory");
    } else {
      asm volatile("s_waitcnt vmcnt(0)" ::: "memory");
    }
    __builtin_amdgcn_s_barrier();            // all waves drained tile tI's loads
    __builtin_amdgcn_sched_barrier(0);       // rule #18: pin reads below the wait
    bf16x8 af[4][2], bfr[4][2];
    #pragma unroll
    for (int mi = 0; mi < 4; mi++){
      int row = wr + mi * 16 + l16;
      #pragma unroll
      for (int s = 0; s < 2; s++){
        int k = s * 32 + lhi * 8;
        int off = row * 128 + ((k * 2) ^ ((row & 7) << 4));
        af[mi][s] = *(const bf16x8*)((const char*)As[cur] + off);
      }
    }
    #pragma unroll
    for (int ni = 0; ni < 4; ni++){
      int row = wc + ni * 16 + l16;
      #pragma unroll
      for (int s = 0; s < 2; s++){
        int k = s * 32 + lhi * 8;
        int off = row * 128 + ((k * 2) ^ ((row & 7) << 4));
        bfr[ni][s] = *(const bf16x8*)((const char*)Bs[cur] + off);
      }
    }
    #pragma unroll
    for (int mi = 0; mi < 4; mi++)
      #pragma unroll
      for (int ni = 0; ni < 4; ni++){
        acc[mi][ni] = __builtin_amdgcn_mfma_f32_16x16x32_bf16(af[mi][0], bfr[ni][0], acc[mi][ni], 0, 0, 0);
        acc[mi][ni] = __builtin_amdgcn_mfma_f32_16x16x32_bf16(af[mi][1], bfr[ni][1], acc[mi][ni], 0, 0, 0);
      }
    // reads consumed (compiler lgkmcnt before MFMAs); barrier -> next iteration
    // may overwrite buf[cur^1] (which iteration tI-1 read).
    __builtin_amdgcn_s_barrier();
    cur ^= 1;
  }

  unsigned short* C = isW ? HB : RB;
  #pragma unroll
  for (int mi = 0; mi < 4; mi++){
    #pragma unroll
    for (int j = 0; j < 4; j++){
      int r = rowA + wr + mi * 16 + lhi * 4 + j;
      unsigned short* Cp = C + (size_t)r * NN + colB + wc + l16;
      #pragma unroll
      for (int ni = 0; ni < 4; ni++)
        Cp[ni * 16] = f2bf(acc[mi][ni][j]);
    }
  }

  if (isW){
    // el/er partials over this wave's 64 columns; store (no atomics) to elp/erp.
    int G = NN >> 6;                    // 64-col groups across nn
    int g64 = (colB + wc) >> 6;
    float alv[4], arv[4];
    #pragma unroll
    for (int ni = 0; ni < 4; ni++){
      int col = colB + wc + ni * 16 + l16;
      alv[ni] = al[col]; arv[ni] = ar[col];
    }
    #pragma unroll
    for (int mi = 0; mi < 4; mi++){
      #pragma unroll
      for (int j = 0; j < 4; j++){
        float pe = acc[mi][0][j]*alv[0] + acc[mi][1][j]*alv[1]
                 + acc[mi][2][j]*alv[2] + acc[mi][3][j]*alv[3];
        float pr = acc[mi][0][j]*arv[0] + acc[mi][1][j]*arv[1]
                 + acc[mi][2][j]*arv[2] + acc[mi][3][j]*arv[3];
        #pragma unroll
        for (int o = 8; o; o >>= 1){ pe += __shfl_xor(pe, o); pr += __shfl_xor(pr, o); }
        if (l16 == 0){
          int r = rowA + wr + mi * 16 + lhi * 4 + j;
          elp[(size_t)r * G + g64] = pe;
          erp[(size_t)r * G + g64] = pr;
        }
      }
    }
  }
}

// ---- reduce el/er partials: one thread per row; G = nn/64, half per head ----
__global__ void k_elred(const float* __restrict__ elp, const float* __restrict__ erp,
                        float* __restrict__ el, float* __restrict__ er, int G){
  int row = blockIdx.x * 256 + threadIdx.x;
  int half = G >> 1;
  float s0 = 0.f, s1 = 0.f, q0 = 0.f, q1 = 0.f;
  const float* ep = elp + (size_t)row * G;
  const float* rp = erp + (size_t)row * G;
  for (int i = 0; i < half; i++){ s0 += ep[i]; q0 += rp[i]; }
  for (int i = half; i < G; i++){ s1 += ep[i]; q1 += rp[i]; }
  el[row*2] = s0; el[row*2+1] = s1;
  er[row*2] = q0; er[row*2+1] = q1;
}

// ---------------- attention: one wave per destination node; RB(bf16) += attn ----------------
template<int D>
__global__ __launch_bounds__(256) void k_attn(const unsigned short* __restrict__ HB,
                                              unsigned short* __restrict__ RB,
                                              const float* __restrict__ el,
                                              const float* __restrict__ er,
                                              const int* __restrict__ rowptr,
                                              const int* __restrict__ perm){
  constexpr int ITER = (2*D)/256;
  int wid = threadIdx.x >> 6, lane = threadIdx.x & 63;
  int nb = (blockIdx.x & 7) * (NNODES/4/8) + (blockIdx.x >> 3);   // bijective: 4096 = 8*512
  int n = nb * 4 + wid;
  int r0 = rowptr[n], r1 = rowptr[n+1];
  if (r0 == r1) return;   // no in-edges: output = residual already in RB
  float er0 = er[n*2], er1 = er[n*2+1];
  float mx0 = -1e30f, mx1 = -1e30f;
  for (int e = r0 + lane; e < r1; e += 64){
    int s = perm[e];
    mx0 = fmaxf(mx0, leaky(el[s*2]   + er0, 0.2f));
    mx1 = fmaxf(mx1, leaky(el[s*2+1] + er1, 0.2f));
  }
  #pragma unroll
  for (int o = 32; o; o >>= 1){ mx0 = fmaxf(mx0, __shfl_xor(mx0, o)); mx1 = fmaxf(mx1, __shfl_xor(mx1, o)); }
  float sm0 = 0.0f, sm1 = 0.0f;
  for (int e = r0 + lane; e < r1; e += 64){
    int s = perm[e];
    sm0 += expf(leaky(el[s*2]   + er0, 0.2f) - mx0);
    sm1 += expf(leaky(el[s*2+1] + er1, 0.2f) - mx1);
  }
  #pragma unroll
  for (int o = 32; o; o >>= 1){ sm0 += __shfl_xor(sm0, o); sm1 += __shfl_xor(sm1, o); }
  float inv0 = 1.0f / sm0, inv1 = 1.0f / sm1;
  float acc[ITER][4];
  #pragma unroll
  for (int j = 0; j < ITER; j++)
    #pragma unroll
    for (int i = 0; i < 4; i++) acc[j][i] = 0.0f;
  for (int e = r0; e < r1; ++e){
    int s = perm[e];
    float a0 = expf(leaky(el[s*2]   + er0, 0.2f) - mx0) * inv0;
    float a1 = expf(leaky(el[s*2+1] + er1, 0.2f) - mx1) * inv1;
    const unsigned short* hrow = HB + (size_t)s * (2*D);
    #pragma unroll
    for (int j = 0; j < ITER; j++){
      int base = j*256 + lane*4;
      bf16x4 v = *(const bf16x4*)(hrow + base);
      float a = (base < D) ? a0 : a1;
      #pragma unroll
      for (int i = 0; i < 4; i++)
        acc[j][i] += a * bf2f((unsigned short)v[i]);
    }
  }
  unsigned short* rrow = RB + (size_t)n * (2*D);
  #pragma unroll
  for (int j = 0; j < ITER; j++){
    int base = j*256 + lane*4;
    bf16x4 r = *(bf16x4*)(rrow + base);
    ushort4 o;
    o.x = f2bf(bf2f((unsigned short)r[0]) + acc[j][0]);
    o.y = f2bf(bf2f((unsigned short)r[1]) + acc[j][1]);
    o.z = f2bf(bf2f((unsigned short)r[2]) + acc[j][2]);
    o.w = f2bf(bf2f((unsigned short)r[3]) + acc[j][3]);
    *(ushort4*)(rrow + base) = o;
  }
}

// ------- GraphNorm stats (bf16 in): grid (NNODES/128, nn/256); lane owns 4 cols -------
__global__ __launch_bounds__(256) void k_stats(const unsigned short* __restrict__ R, int nn,
                                               float* __restrict__ gsum, float* __restrict__ gsq){
  int t = threadIdx.x, lane = t & 63, w = t >> 6;
  int c = blockIdx.y * 256 + lane * 4;
  const unsigned short* base = R + (size_t)(blockIdx.x * 128 + w) * nn + c;
  float4 s = make_float4(0,0,0,0), q = make_float4(0,0,0,0);
  #pragma unroll 4
  for (int i = 0; i < 32; i++){
    bf16x4 bv = *(const bf16x4*)(base + (size_t)(i * 4) * nn);
    float vx = bf2f((unsigned short)bv[0]), vy = bf2f((unsigned short)bv[1]);
    float vz = bf2f((unsigned short)bv[2]), vw = bf2f((unsigned short)bv[3]);
    s.x += vx; s.y += vy; s.z += vz; s.w += vw;
    q.x += vx*vx; q.y += vy*vy; q.z += vz*vz; q.w += vw*vw;
  }
  __shared__ float4 rs[256], rq[256];
  rs[t] = s; rq[t] = q; __syncthreads();
  if (t < 64){
    float4 a = rs[t], b = rs[t+64], c2 = rs[t+128], d2 = rs[t+192];
    float4 e = rq[t], f = rq[t+64], g2 = rq[t+128], h2 = rq[t+192];
    int cc = blockIdx.y * 256 + t * 4;
    atomicAdd(&gsum[cc+0], a.x+b.x+c2.x+d2.x);
    atomicAdd(&gsum[cc+1], a.y+b.y+c2.y+d2.y);
    atomicAdd(&gsum[cc+2], a.z+b.z+c2.z+d2.z);
    atomicAdd(&gsum[cc+3], a.w+b.w+c2.w+d2.w);
    atomicAdd(&gsq [cc+0], e.x+f.x+g2.x+h2.x);
    atomicAdd(&gsq [cc+1], e.y+f.y+g2.y+h2.y);
    atomicAdd(&gsq [cc+2], e.z+f.z+g2.z+h2.z);
    atomicAdd(&gsq [cc+3], e.w+f.w+g2.w+h2.w);
  }
}

// -- norm apply + leaky + head-mean pool (bf16 in) with INLINE stats finalize --
// grid (NNODES/128, nn/256); params are d-length; column c -> channel c & (d-1).
__global__ __launch_bounds__(256) void k_norm_pool(const unsigned short* __restrict__ R,
                                                   unsigned short* __restrict__ Xn, // bf16 next-layer input (or null)
                                                   const float* __restrict__ gsum,
                                                   const float* __restrict__ gsq,
                                                   const float* __restrict__ gamma,
                                                   const float* __restrict__ beta,
                                                   const float* __restrict__ alpha,
                                                   float* __restrict__ pool, int d, int loff){
  int t = threadIdx.x, lane = t & 63, w = t >> 6;
  int c = blockIdx.y * 256 + lane * 4;
  int cm = c & (d - 1);                    // channel index (d-periodic), 4-aligned
  int nodeb = blockIdx.x * 128;
  int g = blockIdx.x >> 3;                 // 8 row-blocks per graph (1024 nodes/graph)
  int nn = 2 * d;
  const float Minv = 1.0f / (2.0f * (float)NNODES);
  float4 gg = *(const float4*)(gamma + cm);
  float4 bb = *(const float4*)(beta + cm);
  float4 aa = *(const float4*)(alpha + cm);
  float mmv[4], rrv[4];
  #pragma unroll
  for (int i = 0; i < 4; i++){
    float m = (gsum[cm+i] + gsum[cm+i+d]) * Minv;
    float q = (gsq [cm+i] + gsq [cm+i+d]) * Minv;
    float a = (i==0)?aa.x:(i==1)?aa.y:(i==2)?aa.z:aa.w;
    float var = q - a * m * m * (2.0f - a);
    mmv[i] = m; rrv[i] = rsqrtf(var + 1e-5f);
  }
  float am0 = aa.x*mmv[0], am1 = aa.y*mmv[1], am2 = aa.z*mmv[2], am3 = aa.w*mmv[3];
  const unsigned short* base = R + (size_t)(nodeb + w) * nn + c;
  unsigned short* xb = Xn ? (Xn + (size_t)(nodeb + w) * nn + c) : nullptr;
  float4 accp = make_float4(0,0,0,0);
  #pragma unroll 4
  for (int i = 0; i < 32; i++){
    bf16x4 bv = *(const bf16x4*)(base + (size_t)(i * 4) * nn);
    float vx = bf2f((unsigned short)bv[0]), vy = bf2f((unsigned short)bv[1]);
    float vz = bf2f((unsigned short)bv[2]), vw = bf2f((unsigned short)bv[3]);
    float y0 = gg.x*(vx-am0)*rrv[0] + bb.x; y0 = y0 >= 0.f ? y0 : 0.01f*y0;
    float y1 = gg.y*(vy-am1)*rrv[1] + bb.y; y1 = y1 >= 0.f ? y1 : 0.01f*y1;
    float y2 = gg.z*(vz-am2)*rrv[2] + bb.z; y2 = y2 >= 0.f ? y2 : 0.01f*y2;
    float y3 = gg.w*(vw-am3)*rrv[3] + bb.w; y3 = y3 >= 0.f ? y3 : 0.01f*y3;
    if (xb){
      ushort4 o; o.x = f2bf(y0); o.y = f2bf(y1); o.z = f2bf(y2); o.w = f2bf(y3);
      *(ushort4*)(xb + (size_t)(i * 4) * nn) = o;
    }
    accp.x += y0; accp.y += y1; accp.z += y2; accp.w += y3;
  }
  __shared__ float4 red[256];
  red[t] = accp; __syncthreads();
  if (t < 64){
    float4 a = red[t], b = red[t+64], c2 = red[t+128], d2 = red[t+192];
    int cc = blockIdx.y * 256 + t * 4;
    float* pb = pool + g * 896 + loff;
    atomicAdd(&pb[(cc+0) & (d-1)], 0.5f*(a.x+b.x+c2.x+d2.x));
    atomicAdd(&pb[(cc+1) & (d-1)], 0.5f*(a.y+b.y+c2.y+d2.y));
    atomicAdd(&pb[(cc+2) & (d-1)], 0.5f*(a.z+b.z+c2.z+d2.z));
    atomicAdd(&pb[(cc+3) & (d-1)], 0.5f*(a.w+b.w+c2.w+d2.w));
  }
}

__global__ void k_final(const float* __restrict__ pool, const float* __restrict__ counts,
                        float* __restrict__ out){
  int idx = blockIdx.x * 256 + threadIdx.x;
  if (idx >= NGRAPHS * 896) return;
  int g = idx / 896;
  float v = pool[idx] / counts[g];
  out[idx] = v >= 0.0f ? v : 0.01f * v;
}

// ---------------------------------------------------------------------------------------
extern "C" void kernel_launch(void* const* d_in, const int* in_sizes, int n_in,
                              void* d_out, int out_size, void* d_ws, size_t ws_size,
                              hipStream_t stream){
  const float* x0 = (const float*)d_in[0];
  const float *W[3], *AL[3], *AR[3], *RW[3], *GA[3], *BE[3], *ALP[3];
  for (int l = 0; l < 3; l++){
    const int b = 1 + l*7;
    W[l]  = (const float*)d_in[b+0];
    AL[l] = (const float*)d_in[b+1];
    AR[l] = (const float*)d_in[b+2];
    RW[l] = (const float*)d_in[b+3];
    GA[l] = (const float*)d_in[b+4];
    BE[l] = (const float*)d_in[b+5];
    ALP[l]= (const float*)d_in[b+6];
  }
  const int* esrc = (const int*)d_in[22];
  const int* edst = (const int*)d_in[23];
  const int* gid  = (const int*)d_in[24];
  float* out = (float*)d_out;

  char* p = (char*)d_ws;
  auto carve = [&](size_t bytes)->void*{
    void* r = (void*)p; p += (bytes + 255) & ~(size_t)255; return r;
  };
  unsigned short* HB = (unsigned short*)carve((size_t)NNODES * 1024 * 2);  // h bf16 [N, 2d]
  unsigned short* RB = (unsigned short*)carve((size_t)NNODES * 1024 * 2);  // r/out bf16 [N, 2d]
  unsigned short* X0b = (unsigned short*)carve((size_t)NNODES * 128 * 2);  // bf16 layer-0 input
  unsigned short* XA  = (unsigned short*)carve((size_t)NNODES * 256 * 2);  // bf16 y0
  unsigned short* XB  = (unsigned short*)carve((size_t)NNODES * 512 * 2);  // bf16 y1
  unsigned short* Wt  = (unsigned short*)carve((size_t)1024 * 512 * 2);    // bf16 W^T (max)
  unsigned short* RWt = (unsigned short*)carve((size_t)1024 * 512 * 2);    // bf16 resW^T (max)
  float* el     = (float*)carve((size_t)NNODES * 2 * 4);
  float* er     = (float*)carve((size_t)NNODES * 2 * 4);
  float* elp    = (float*)carve((size_t)NNODES * 16 * 4);    // el partials (G<=16)
  float* erp    = (float*)carve((size_t)NNODES * 16 * 4);    // er partials
  int*   deg    = (int*)  carve((size_t)NNODES * 4);
  int*   rowptr = (int*)  carve((size_t)(NNODES + 1) * 4);
  int*   cursor = (int*)  carve((size_t)NNODES * 4);
  int*   perm   = (int*)  carve((size_t)NEDGES * 4);
  float* stats  = (float*)carve(2048 * 4);                   // gsum[1024] | gsq[1024]
  float* pool   = (float*)carve((size_t)NGRAPHS * 896 * 4);
  float* countsF= (float*)carve((size_t)NGRAPHS * 4);
  (void)ws_size; (void)in_sizes; (void)n_in; (void)out_size;

  hipMemsetAsync(deg, 0, NNODES * 4, stream);
  hipMemsetAsync(pool, 0, NGRAPHS * 896 * 4, stream);
  hipMemsetAsync(countsF, 0, NGRAPHS * 4, stream);

  k_deg    <<<NEDGES/256, 256, 0, stream>>>(edst, deg);
  k_scan   <<<1, 1024, 0, stream>>>(deg, rowptr, cursor);
  k_scatter<<<NEDGES/256, 256, 0, stream>>>(esrc, edst, cursor, perm);
  k_counts <<<NNODES/1024, 256, 0, stream>>>(gid, countsF);
  k_cvt    <<<(NNODES*128/4 + 255)/256, 256, 0, stream>>>(x0, X0b, NNODES*128/4);

  const unsigned short* xin = X0b;
  int loff = 0;
  const int dims[3] = {128, 256, 512};
  for (int l = 0; l < 3; l++){
    int d = dims[l], nn = 2*d;
    dim3 gt(nn/32, d/32, 2);
    k_cvt_t2<<<gt, 256, 0, stream>>>(W[l], RW[l], Wt, RWt, d, nn);
    dim3 gg(2*nn/128, NNODES/128);
    k_gemm2<<<gg, 256, 0, stream>>>(xin, Wt, RWt, HB, RB, AL[l], AR[l], elp, erp, d, nn);
    k_elred<<<NNODES/256, 256, 0, stream>>>(elp, erp, el, er, nn >> 6);
    if (d == 128){
      k_attn<128><<<NNODES/4, 256, 0, stream>>>(HB, RB, el, er, rowptr, perm);
    } else if (d == 256){
      k_attn<256><<<NNODES/4, 256, 0, stream>>>(HB, RB, el, er, rowptr, perm);
    } else {
      k_attn<512><<<NNODES/4, 256, 0, stream>>>(HB, RB, el, er, rowptr, perm);
    }
    hipMemsetAsync(stats, 0, 2048 * 4, stream);
    dim3 gs(NNODES/128, nn/256);
    k_stats   <<<gs, 256, 0, stream>>>(RB, nn, stats, stats + 1024);
    unsigned short* xn = (l == 0) ? XA : (l == 1) ? XB : nullptr;
    k_norm_pool<<<gs, 256, 0, stream>>>(RB, xn, stats, stats + 1024, GA[l], BE[l], ALP[l], pool, d, loff);
    xin = xn; loff += d;
  }
  k_final<<<(NGRAPHS*896 + 255)/256, 256, 0, stream>>>(pool, countsF, out);
}

// Round 17
// 338.469 us; speedup vs baseline: 1.1275x; 1.0014x over previous
//
#include <hip/hip_runtime.h>
#include <math.h>

constexpr int NNODES  = 16384;
constexpr int NEDGES  = 131072;
constexpr int NGRAPHS = 16;

typedef short bf16x8 __attribute__((ext_vector_type(8)));
typedef short bf16x4 __attribute__((ext_vector_type(4)));
typedef float f32x4  __attribute__((ext_vector_type(4)));

__device__ __forceinline__ float leaky(float x, float s){ return x >= 0.0f ? x : s * x; }

__device__ __forceinline__ unsigned short f2bf(float f){
  unsigned u = __builtin_bit_cast(unsigned, f);
  u += 0x7FFFu + ((u >> 16) & 1u);          // round-to-nearest-even
  return (unsigned short)(u >> 16);
}
__device__ __forceinline__ float bf2f(unsigned short u){
  unsigned x = (unsigned)u << 16; return __builtin_bit_cast(float, x);
}

__device__ __forceinline__ void gload_lds16(const unsigned short* g, unsigned short* l){
  __builtin_amdgcn_global_load_lds((const __attribute__((address_space(1))) void*)g,
                                   (__attribute__((address_space(3))) void*)l, 16, 0, 0);
}

// ---------------- CSR build (edges fixed across layers; build once) ----------------
__global__ void k_deg(const int* __restrict__ dst, int* __restrict__ deg){
  int e = blockIdx.x * 256 + threadIdx.x;
  if (e < NEDGES) atomicAdd(&deg[dst[e]], 1);
}

__global__ __launch_bounds__(1024) void k_scan(const int* __restrict__ deg,
                                               int* __restrict__ rowptr,
                                               int* __restrict__ cursor){
  __shared__ int sums[1024];
  int t = threadIdx.x;
  int loc[16];
  int s = 0;
  #pragma unroll
  for (int i = 0; i < 16; i++){ loc[i] = deg[t*16 + i]; s += loc[i]; }
  sums[t] = s; __syncthreads();
  for (int off = 1; off < 1024; off <<= 1){
    int v = (t >= off) ? sums[t - off] : 0;
    __syncthreads();
    sums[t] += v;
    __syncthreads();
  }
  int base = (t > 0) ? sums[t-1] : 0;
  #pragma unroll
  for (int i = 0; i < 16; i++){
    rowptr[t*16 + i] = base; cursor[t*16 + i] = base; base += loc[i];
  }
  if (t == 1023) rowptr[NNODES] = base;
}

__global__ void k_scatter(const int* __restrict__ src, const int* __restrict__ dst,
                          int* __restrict__ cursor, int* __restrict__ perm){
  int e = blockIdx.x * 256 + threadIdx.x;
  if (e < NEDGES){ int p = atomicAdd(&cursor[dst[e]], 1); perm[p] = src[e]; }
}

// ---- graph-size counts: LDS histogram per block, one global atomic per (block,graph) ----
__global__ __launch_bounds__(256) void k_counts(const int* __restrict__ gid, float* __restrict__ counts){
  __shared__ int h[NGRAPHS];
  int t = threadIdx.x;
  if (t < NGRAPHS) h[t] = 0;
  __syncthreads();
  int base = blockIdx.x * 1024;
  #pragma unroll
  for (int i = 0; i < 4; i++)
    atomicAdd(&h[gid[base + t + i*256]], 1);
  __syncthreads();
  if (t < NGRAPHS && h[t] > 0) atomicAdd(&counts[t], (float)h[t]);
}

// ---------------- fp32 -> bf16 convert (contiguous) ----------------
__global__ void k_cvt(const float* __restrict__ in, unsigned short* __restrict__ out, int n4){
  int i = blockIdx.x * 256 + threadIdx.x;
  if (i >= n4) return;
  float4 v = ((const float4*)in)[i];
  ushort4 o; o.x = f2bf(v.x); o.y = f2bf(v.y); o.z = f2bf(v.z); o.w = f2bf(v.w);
  ((ushort4*)out)[i] = o;
}

// -------- fp32 [K][NN] -> bf16 transposed [NN][K], both W and RW in one launch --------
__global__ __launch_bounds__(256) void k_cvt_t2(const float* __restrict__ W,
                                                const float* __restrict__ RW,
                                                unsigned short* __restrict__ Wt,
                                                unsigned short* __restrict__ RWt,
                                                int K, int NN){
  __shared__ float tile[32][33];
  const float* src = blockIdx.z ? RW : W;
  unsigned short* dst = blockIdx.z ? RWt : Wt;
  int n0 = blockIdx.x * 32, k0 = blockIdx.y * 32;
  int tx = threadIdx.x & 31, ty = threadIdx.x >> 5;   // 32 x 8
  #pragma unroll
  for (int i = 0; i < 4; i++)
    tile[ty + i*8][tx] = src[(size_t)(k0 + ty + i*8) * NN + n0 + tx];
  __syncthreads();
  #pragma unroll
  for (int i = 0; i < 4; i++)
    dst[(size_t)(n0 + ty + i*8) * K + k0 + tx] = f2bf(tile[tx][ty + i*8]);
}

// ------- fused dual bf16 MFMA GEMM (BK=32, 5 blocks/CU, counted-vmcnt pipeline) -------
// 128x128 tile, BK=32, double-buffered LDS (2 x 16KB = 32KB -> 5 blocks/CU, 20
// waves/CU). Per K-step: issue 4 next-tile global_load_lds, s_waitcnt vmcnt(4)
// (drains only the current tile's 4), s_barrier, ds_read+16 MFMA, s_barrier.
// LDS rows are 64B; swizzle: 16B-slot ^= (row&3)<<4 applied to BOTH the
// pre-swizzled global source and the ds_read offset (involution).
// W-half epilogue: per-64-col el/er partial dots -> elp/erp (plain stores).
__global__ __launch_bounds__(256) void k_gemm2(const unsigned short* __restrict__ A,
                                               const unsigned short* __restrict__ Wt,
                                               const unsigned short* __restrict__ RWt,
                                               unsigned short* __restrict__ HB,
                                               unsigned short* __restrict__ RB,
                                               const float* __restrict__ al,
                                               const float* __restrict__ ar,
                                               float* __restrict__ elp,
                                               float* __restrict__ erp,
                                               int K, int NN){
  __shared__ unsigned short As[2][128 * 32];
  __shared__ unsigned short Bs[2][128 * 32];
  int t = threadIdx.x;
  int lane = t & 63, w = t >> 6;
  int nx  = gridDim.x;                       // 2*NN/128
  int nwg = nx * gridDim.y;                  // multiple of 8
  int bid = blockIdx.x + blockIdx.y * nx;
  int wg  = (bid & 7) * (nwg >> 3) + (bid >> 3);
  int bx = wg % nx, by = wg / nx;
  int half = nx >> 1;
  bool isW = bx < half;
  const unsigned short* Bt = isW ? Wt : RWt;
  int colB = (isW ? bx : bx - half) * 128;
  int rowA = by * 128;

  int wr = (w >> 1) * 64, wc = (w & 1) * 64;
  int l16 = lane & 15, lhi = lane >> 4;
  f32x4 acc[4][4] = {};

  // staging: 512 chunks of 16B per matrix/tile; thread t -> chunks t and t+256.
  // chunk c: row = c>>2, slot = c&3; global kbyte = (slot<<4) ^ ((row&3)<<4).
  int srow = t >> 2;                               // 0..63 (chunk t); +64 for chunk t+256
  int skb  = ((t & 3) << 4) ^ ((srow & 3) << 4);   // bytes, lane-constant (row&3 same for srow+64)
  const unsigned short* Ap = A  + (size_t)(rowA + srow) * K + (skb >> 1);
  const unsigned short* Bp = Bt + (size_t)(colB + srow) * K + (skb >> 1);
  size_t rstep = (size_t)64 * K;                   // +64 rows

  int nt = K >> 5;
  // prologue: stage tile 0 into buf 0 (4 loads in flight; no drain yet)
  gload_lds16(Ap,         &As[0][t * 8]);
  gload_lds16(Ap + rstep, &As[0][(t + 256) * 8]);
  gload_lds16(Bp,         &Bs[0][t * 8]);
  gload_lds16(Bp + rstep, &Bs[0][(t + 256) * 8]);

  int cur = 0;
  for (int tI = 0; tI < nt; tI++){
    if (tI + 1 < nt){
      int k0n = (tI + 1) << 5;
      gload_lds16(Ap + k0n,         &As[cur ^ 1][t * 8]);
      gload_lds16(Ap + k0n + rstep, &As[cur ^ 1][(t + 256) * 8]);
      gload_lds16(Bp + k0n,         &Bs[cur ^ 1][t * 8]);
      gload_lds16(Bp + k0n + rstep, &Bs[cur ^ 1][(t + 256) * 8]);
      // outstanding = 8; wait until <=4 -> the 4 current-tile loads landed
      asm volatile("s_waitcnt vmcnt(4)" ::: "memory");
    } else {
      asm volatile("s_waitcnt vmcnt(0)" ::: "memory");
    }
    __builtin_amdgcn_s_barrier();            // all waves drained tile tI's loads
    __builtin_amdgcn_sched_barrier(0);       // rule #18: pin reads below the wait
    int kb = lhi * 16;                       // this lane's 16B k-slot
    bf16x8 af[4], bfr[4];
    #pragma unroll
    for (int mi = 0; mi < 4; mi++){
      int row = wr + mi * 16 + l16;
      int off = row * 64 + (kb ^ ((row & 3) << 4));
      af[mi] = *(const bf16x8*)((const char*)As[cur] + off);
    }
    #pragma unroll
    for (int ni = 0; ni < 4; ni++){
      int row = wc + ni * 16 + l16;
      int off = row * 64 + (kb ^ ((row & 3) << 4));
      bfr[ni] = *(const bf16x8*)((const char*)Bs[cur] + off);
    }
    #pragma unroll
    for (int mi = 0; mi < 4; mi++)
      #pragma unroll
      for (int ni = 0; ni < 4; ni++)
        acc[mi][ni] = __builtin_amdgcn_mfma_f32_16x16x32_bf16(af[mi], bfr[ni], acc[mi][ni], 0, 0, 0);
    // reads consumed (compiler lgkmcnt before MFMAs); next iter may overwrite other buf
    __builtin_amdgcn_s_barrier();
    cur ^= 1;
  }

  unsigned short* C = isW ? HB : RB;
  #pragma unroll
  for (int mi = 0; mi < 4; mi++){
    #pragma unroll
    for (int j = 0; j < 4; j++){
      int r = rowA + wr + mi * 16 + lhi * 4 + j;
      unsigned short* Cp = C + (size_t)r * NN + colB + wc + l16;
      #pragma unroll
      for (int ni = 0; ni < 4; ni++)
        Cp[ni * 16] = f2bf(acc[mi][ni][j]);
    }
  }

  if (isW){
    // el/er partials over this wave's 64 columns; store (no atomics) to elp/erp.
    int G = NN >> 6;                    // 64-col groups across nn
    int g64 = (colB + wc) >> 6;
    float alv[4], arv[4];
    #pragma unroll
    for (int ni = 0; ni < 4; ni++){
      int col = colB + wc + ni * 16 + l16;
      alv[ni] = al[col]; arv[ni] = ar[col];
    }
    #pragma unroll
    for (int mi = 0; mi < 4; mi++){
      #pragma unroll
      for (int j = 0; j < 4; j++){
        float pe = acc[mi][0][j]*alv[0] + acc[mi][1][j]*alv[1]
                 + acc[mi][2][j]*alv[2] + acc[mi][3][j]*alv[3];
        float pr = acc[mi][0][j]*arv[0] + acc[mi][1][j]*arv[1]
                 + acc[mi][2][j]*arv[2] + acc[mi][3][j]*arv[3];
        #pragma unroll
        for (int o = 8; o; o >>= 1){ pe += __shfl_xor(pe, o); pr += __shfl_xor(pr, o); }
        if (l16 == 0){
          int r = rowA + wr + mi * 16 + lhi * 4 + j;
          elp[(size_t)r * G + g64] = pe;
          erp[(size_t)r * G + g64] = pr;
        }
      }
    }
  }
}

// ---- reduce el/er partials: one thread per row; G = nn/64, half per head ----
__global__ void k_elred(const float* __restrict__ elp, const float* __restrict__ erp,
                        float* __restrict__ el, float* __restrict__ er, int G){
  int row = blockIdx.x * 256 + threadIdx.x;
  int half = G >> 1;
  float s0 = 0.f, s1 = 0.f, q0 = 0.f, q1 = 0.f;
  const float* ep = elp + (size_t)row * G;
  const float* rp = erp + (size_t)row * G;
  for (int i = 0; i < half; i++){ s0 += ep[i]; q0 += rp[i]; }
  for (int i = half; i < G; i++){ s1 += ep[i]; q1 += rp[i]; }
  el[row*2] = s0; el[row*2+1] = s1;
  er[row*2] = q0; er[row*2+1] = q1;
}

// ---------------- attention: one wave per destination node; RB(bf16) += attn ----------------
template<int D>
__global__ __launch_bounds__(256) void k_attn(const unsigned short* __restrict__ HB,
                                              unsigned short* __restrict__ RB,
                                              const float* __restrict__ el,
                                              const float* __restrict__ er,
                                              const int* __restrict__ rowptr,
                                              const int* __restrict__ perm){
  constexpr int ITER = (2*D)/256;
  int wid = threadIdx.x >> 6, lane = threadIdx.x & 63;
  int nb = (blockIdx.x & 7) * (NNODES/4/8) + (blockIdx.x >> 3);   // bijective: 4096 = 8*512
  int n = nb * 4 + wid;
  int r0 = rowptr[n], r1 = rowptr[n+1];
  if (r0 == r1) return;   // no in-edges: output = residual already in RB
  float er0 = er[n*2], er1 = er[n*2+1];
  float mx0 = -1e30f, mx1 = -1e30f;
  for (int e = r0 + lane; e < r1; e += 64){
    int s = perm[e];
    mx0 = fmaxf(mx0, leaky(el[s*2]   + er0, 0.2f));
    mx1 = fmaxf(mx1, leaky(el[s*2+1] + er1, 0.2f));
  }
  #pragma unroll
  for (int o = 32; o; o >>= 1){ mx0 = fmaxf(mx0, __shfl_xor(mx0, o)); mx1 = fmaxf(mx1, __shfl_xor(mx1, o)); }
  float sm0 = 0.0f, sm1 = 0.0f;
  for (int e = r0 + lane; e < r1; e += 64){
    int s = perm[e];
    sm0 += expf(leaky(el[s*2]   + er0, 0.2f) - mx0);
    sm1 += expf(leaky(el[s*2+1] + er1, 0.2f) - mx1);
  }
  #pragma unroll
  for (int o = 32; o; o >>= 1){ sm0 += __shfl_xor(sm0, o); sm1 += __shfl_xor(sm1, o); }
  float inv0 = 1.0f / sm0, inv1 = 1.0f / sm1;
  float acc[ITER][4];
  #pragma unroll
  for (int j = 0; j < ITER; j++)
    #pragma unroll
    for (int i = 0; i < 4; i++) acc[j][i] = 0.0f;
  for (int e = r0; e < r1; ++e){
    int s = perm[e];
    float a0 = expf(leaky(el[s*2]   + er0, 0.2f) - mx0) * inv0;
    float a1 = expf(leaky(el[s*2+1] + er1, 0.2f) - mx1) * inv1;
    const unsigned short* hrow = HB + (size_t)s * (2*D);
    #pragma unroll
    for (int j = 0; j < ITER; j++){
      int base = j*256 + lane*4;
      bf16x4 v = *(const bf16x4*)(hrow + base);
      float a = (base < D) ? a0 : a1;
      #pragma unroll
      for (int i = 0; i < 4; i++)
        acc[j][i] += a * bf2f((unsigned short)v[i]);
    }
  }
  unsigned short* rrow = RB + (size_t)n * (2*D);
  #pragma unroll
  for (int j = 0; j < ITER; j++){
    int base = j*256 + lane*4;
    bf16x4 r = *(bf16x4*)(rrow + base);
    ushort4 o;
    o.x = f2bf(bf2f((unsigned short)r[0]) + acc[j][0]);
    o.y = f2bf(bf2f((unsigned short)r[1]) + acc[j][1]);
    o.z = f2bf(bf2f((unsigned short)r[2]) + acc[j][2]);
    o.w = f2bf(bf2f((unsigned short)r[3]) + acc[j][3]);
    *(ushort4*)(rrow + base) = o;
  }
}

// ------- GraphNorm stats (bf16 in): grid (NNODES/128, nn/256); lane owns 4 cols -------
__global__ __launch_bounds__(256) void k_stats(const unsigned short* __restrict__ R, int nn,
                                               float* __restrict__ gsum, float* __restrict__ gsq){
  int t = threadIdx.x, lane = t & 63, w = t >> 6;
  int c = blockIdx.y * 256 + lane * 4;
  const unsigned short* base = R + (size_t)(blockIdx.x * 128 + w) * nn + c;
  float4 s = make_float4(0,0,0,0), q = make_float4(0,0,0,0);
  #pragma unroll 4
  for (int i = 0; i < 32; i++){
    bf16x4 bv = *(const bf16x4*)(base + (size_t)(i * 4) * nn);
    float vx = bf2f((unsigned short)bv[0]), vy = bf2f((unsigned short)bv[1]);
    float vz = bf2f((unsigned short)bv[2]), vw = bf2f((unsigned short)bv[3]);
    s.x += vx; s.y += vy; s.z += vz; s.w += vw;
    q.x += vx*vx; q.y += vy*vy; q.z += vz*vz; q.w += vw*vw;
  }
  __shared__ float4 rs[256], rq[256];
  rs[t] = s; rq[t] = q; __syncthreads();
  if (t < 64){
    float4 a = rs[t], b = rs[t+64], c2 = rs[t+128], d2 = rs[t+192];
    float4 e = rq[t], f = rq[t+64], g2 = rq[t+128], h2 = rq[t+192];
    int cc = blockIdx.y * 256 + t * 4;
    atomicAdd(&gsum[cc+0], a.x+b.x+c2.x+d2.x);
    atomicAdd(&gsum[cc+1], a.y+b.y+c2.y+d2.y);
    atomicAdd(&gsum[cc+2], a.z+b.z+c2.z+d2.z);
    atomicAdd(&gsum[cc+3], a.w+b.w+c2.w+d2.w);
    atomicAdd(&gsq [cc+0], e.x+f.x+g2.x+h2.x);
    atomicAdd(&gsq [cc+1], e.y+f.y+g2.y+h2.y);
    atomicAdd(&gsq [cc+2], e.z+f.z+g2.z+h2.z);
    atomicAdd(&gsq [cc+3], e.w+f.w+g2.w+h2.w);
  }
}

// -- norm apply + leaky + head-mean pool (bf16 in) with INLINE stats finalize --
// grid (NNODES/128, nn/256); params are d-length; column c -> channel c & (d-1).
__global__ __launch_bounds__(256) void k_norm_pool(const unsigned short* __restrict__ R,
                                                   unsigned short* __restrict__ Xn, // bf16 next-layer input (or null)
                                                   const float* __restrict__ gsum,
                                                   const float* __restrict__ gsq,
                                                   const float* __restrict__ gamma,
                                                   const float* __restrict__ beta,
                                                   const float* __restrict__ alpha,
                                                   float* __restrict__ pool, int d, int loff){
  int t = threadIdx.x, lane = t & 63, w = t >> 6;
  int c = blockIdx.y * 256 + lane * 4;
  int cm = c & (d - 1);                    // channel index (d-periodic), 4-aligned
  int nodeb = blockIdx.x * 128;
  int g = blockIdx.x >> 3;                 // 8 row-blocks per graph (1024 nodes/graph)
  int nn = 2 * d;
  const float Minv = 1.0f / (2.0f * (float)NNODES);
  float4 gg = *(const float4*)(gamma + cm);
  float4 bb = *(const float4*)(beta + cm);
  float4 aa = *(const float4*)(alpha + cm);
  float mmv[4], rrv[4];
  #pragma unroll
  for (int i = 0; i < 4; i++){
    float m = (gsum[cm+i] + gsum[cm+i+d]) * Minv;
    float q = (gsq [cm+i] + gsq [cm+i+d]) * Minv;
    float a = (i==0)?aa.x:(i==1)?aa.y:(i==2)?aa.z:aa.w;
    float var = q - a * m * m * (2.0f - a);
    mmv[i] = m; rrv[i] = rsqrtf(var + 1e-5f);
  }
  float am0 = aa.x*mmv[0], am1 = aa.y*mmv[1], am2 = aa.z*mmv[2], am3 = aa.w*mmv[3];
  const unsigned short* base = R + (size_t)(nodeb + w) * nn + c;
  unsigned short* xb = Xn ? (Xn + (size_t)(nodeb + w) * nn + c) : nullptr;
  float4 accp = make_float4(0,0,0,0);
  #pragma unroll 4
  for (int i = 0; i < 32; i++){
    bf16x4 bv = *(const bf16x4*)(base + (size_t)(i * 4) * nn);
    float vx = bf2f((unsigned short)bv[0]), vy = bf2f((unsigned short)bv[1]);
    float vz = bf2f((unsigned short)bv[2]), vw = bf2f((unsigned short)bv[3]);
    float y0 = gg.x*(vx-am0)*rrv[0] + bb.x; y0 = y0 >= 0.f ? y0 : 0.01f*y0;
    float y1 = gg.y*(vy-am1)*rrv[1] + bb.y; y1 = y1 >= 0.f ? y1 : 0.01f*y1;
    float y2 = gg.z*(vz-am2)*rrv[2] + bb.z; y2 = y2 >= 0.f ? y2 : 0.01f*y2;
    float y3 = gg.w*(vw-am3)*rrv[3] + bb.w; y3 = y3 >= 0.f ? y3 : 0.01f*y3;
    if (xb){
      ushort4 o; o.x = f2bf(y0); o.y = f2bf(y1); o.z = f2bf(y2); o.w = f2bf(y3);
      *(ushort4*)(xb + (size_t)(i * 4) * nn) = o;
    }
    accp.x += y0; accp.y += y1; accp.z += y2; accp.w += y3;
  }
  __shared__ float4 red[256];
  red[t] = accp; __syncthreads();
  if (t < 64){
    float4 a = red[t], b = red[t+64], c2 = red[t+128], d2 = red[t+192];
    int cc = blockIdx.y * 256 + t * 4;
    float* pb = pool + g * 896 + loff;
    atomicAdd(&pb[(cc+0) & (d-1)], 0.5f*(a.x+b.x+c2.x+d2.x));
    atomicAdd(&pb[(cc+1) & (d-1)], 0.5f*(a.y+b.y+c2.y+d2.y));
    atomicAdd(&pb[(cc+2) & (d-1)], 0.5f*(a.z+b.z+c2.z+d2.z));
    atomicAdd(&pb[(cc+3) & (d-1)], 0.5f*(a.w+b.w+c2.w+d2.w));
  }
}

__global__ void k_final(const float* __restrict__ pool, const float* __restrict__ counts,
                        float* __restrict__ out){
  int idx = blockIdx.x * 256 + threadIdx.x;
  if (idx >= NGRAPHS * 896) return;
  int g = idx / 896;
  float v = pool[idx] / counts[g];
  out[idx] = v >= 0.0f ? v : 0.01f * v;
}

// ---------------------------------------------------------------------------------------
extern "C" void kernel_launch(void* const* d_in, const int* in_sizes, int n_in,
                              void* d_out, int out_size, void* d_ws, size_t ws_size,
                              hipStream_t stream){
  const float* x0 = (const float*)d_in[0];
  const float *W[3], *AL[3], *AR[3], *RW[3], *GA[3], *BE[3], *ALP[3];
  for (int l = 0; l < 3; l++){
    const int b = 1 + l*7;
    W[l]  = (const float*)d_in[b+0];
    AL[l] = (const float*)d_in[b+1];
    AR[l] = (const float*)d_in[b+2];
    RW[l] = (const float*)d_in[b+3];
    GA[l] = (const float*)d_in[b+4];
    BE[l] = (const float*)d_in[b+5];
    ALP[l]= (const float*)d_in[b+6];
  }
  const int* esrc = (const int*)d_in[22];
  const int* edst = (const int*)d_in[23];
  const int* gid  = (const int*)d_in[24];
  float* out = (float*)d_out;

  char* p = (char*)d_ws;
  auto carve = [&](size_t bytes)->void*{
    void* r = (void*)p; p += (bytes + 255) & ~(size_t)255; return r;
  };
  unsigned short* HB = (unsigned short*)carve((size_t)NNODES * 1024 * 2);  // h bf16 [N, 2d]
  unsigned short* RB = (unsigned short*)carve((size_t)NNODES * 1024 * 2);  // r/out bf16 [N, 2d]
  unsigned short* X0b = (unsigned short*)carve((size_t)NNODES * 128 * 2);  // bf16 layer-0 input
  unsigned short* XA  = (unsigned short*)carve((size_t)NNODES * 256 * 2);  // bf16 y0
  unsigned short* XB  = (unsigned short*)carve((size_t)NNODES * 512 * 2);  // bf16 y1
  unsigned short* Wt  = (unsigned short*)carve((size_t)1024 * 512 * 2);    // bf16 W^T (max)
  unsigned short* RWt = (unsigned short*)carve((size_t)1024 * 512 * 2);    // bf16 resW^T (max)
  float* el     = (float*)carve((size_t)NNODES * 2 * 4);
  float* er     = (float*)carve((size_t)NNODES * 2 * 4);
  float* elp    = (float*)carve((size_t)NNODES * 16 * 4);    // el partials (G<=16)
  float* erp    = (float*)carve((size_t)NNODES * 16 * 4);    // er partials
  int*   deg    = (int*)  carve((size_t)NNODES * 4);
  int*   rowptr = (int*)  carve((size_t)(NNODES + 1) * 4);
  int*   cursor = (int*)  carve((size_t)NNODES * 4);
  int*   perm   = (int*)  carve((size_t)NEDGES * 4);
  float* stats  = (float*)carve(2048 * 4);                   // gsum[1024] | gsq[1024]
  float* pool   = (float*)carve((size_t)NGRAPHS * 896 * 4);
  float* countsF= (float*)carve((size_t)NGRAPHS * 4);
  (void)ws_size; (void)in_sizes; (void)n_in; (void)out_size;

  hipMemsetAsync(deg, 0, NNODES * 4, stream);
  hipMemsetAsync(pool, 0, NGRAPHS * 896 * 4, stream);
  hipMemsetAsync(countsF, 0, NGRAPHS * 4, stream);

  k_deg    <<<NEDGES/256, 256, 0, stream>>>(edst, deg);
  k_scan   <<<1, 1024, 0, stream>>>(deg, rowptr, cursor);
  k_scatter<<<NEDGES/256, 256, 0, stream>>>(esrc, edst, cursor, perm);
  k_counts <<<NNODES/1024, 256, 0, stream>>>(gid, countsF);
  k_cvt    <<<(NNODES*128/4 + 255)/256, 256, 0, stream>>>(x0, X0b, NNODES*128/4);

  const unsigned short* xin = X0b;
  int loff = 0;
  const int dims[3] = {128, 256, 512};
  for (int l = 0; l < 3; l++){
    int d = dims[l], nn = 2*d;
    dim3 gt(nn/32, d/32, 2);
    k_cvt_t2<<<gt, 256, 0, stream>>>(W[l], RW[l], Wt, RWt, d, nn);
    dim3 gg(2*nn/128, NNODES/128);
    k_gemm2<<<gg, 256, 0, stream>>>(xin, Wt, RWt, HB, RB, AL[l], AR[l], elp, erp, d, nn);
    k_elred<<<NNODES/256, 256, 0, stream>>>(elp, erp, el, er, nn >> 6);
    if (d == 128){
      k_attn<128><<<NNODES/4, 256, 0, stream>>>(HB, RB, el, er, rowptr, perm);
    } else if (d == 256){
      k_attn<256><<<NNODES/4, 256, 0, stream>>>(HB, RB, el, er, rowptr, perm);
    } else {
      k_attn<512><<<NNODES/4, 256, 0, stream>>>(HB, RB, el, er, rowptr, perm);
    }
    hipMemsetAsync(stats, 0, 2048 * 4, stream);
    dim3 gs(NNODES/128, nn/256);
    k_stats   <<<gs, 256, 0, stream>>>(RB, nn, stats, stats + 1024);
    unsigned short* xn = (l == 0) ? XA : (l == 1) ? XB : nullptr;
    k_norm_pool<<<gs, 256, 0, stream>>>(RB, xn, stats, stats + 1024, GA[l], BE[l], ALP[l], pool, d, loff);
    xin = xn; loff += d;
  }
  k_final<<<(NGRAPHS*896 + 255)/256, 256, 0, stream>>>(pool, countsF, out);
}

// Round 18
// 336.163 us; speedup vs baseline: 1.1353x; 1.0069x over previous
//
#include <hip/hip_runtime.h>
#include <math.h>

constexpr int NNODES  = 16384;
constexpr int NEDGES  = 131072;
constexpr int NGRAPHS = 16;

typedef short bf16x8 __attribute__((ext_vector_type(8)));
typedef short bf16x4 __attribute__((ext_vector_type(4)));
typedef float f32x4  __attribute__((ext_vector_type(4)));

__device__ __forceinline__ float leaky(float x, float s){ return x >= 0.0f ? x : s * x; }

__device__ __forceinline__ unsigned short f2bf(float f){
  unsigned u = __builtin_bit_cast(unsigned, f);
  u += 0x7FFFu + ((u >> 16) & 1u);          // round-to-nearest-even
  return (unsigned short)(u >> 16);
}
__device__ __forceinline__ float bf2f(unsigned short u){
  unsigned x = (unsigned)u << 16; return __builtin_bit_cast(float, x);
}

__device__ __forceinline__ void gload_lds16(const unsigned short* g, unsigned short* l){
  __builtin_amdgcn_global_load_lds((const __attribute__((address_space(1))) void*)g,
                                   (__attribute__((address_space(3))) void*)l, 16, 0, 0);
}

// ---------------- CSR build (edges fixed across layers; build once) ----------------
__global__ void k_deg(const int* __restrict__ dst, int* __restrict__ deg){
  int e = blockIdx.x * 256 + threadIdx.x;
  if (e < NEDGES) atomicAdd(&deg[dst[e]], 1);
}

__global__ __launch_bounds__(1024) void k_scan(const int* __restrict__ deg,
                                               int* __restrict__ rowptr,
                                               int* __restrict__ cursor){
  __shared__ int sums[1024];
  int t = threadIdx.x;
  int loc[16];
  int s = 0;
  #pragma unroll
  for (int i = 0; i < 16; i++){ loc[i] = deg[t*16 + i]; s += loc[i]; }
  sums[t] = s; __syncthreads();
  for (int off = 1; off < 1024; off <<= 1){
    int v = (t >= off) ? sums[t - off] : 0;
    __syncthreads();
    sums[t] += v;
    __syncthreads();
  }
  int base = (t > 0) ? sums[t-1] : 0;
  #pragma unroll
  for (int i = 0; i < 16; i++){
    rowptr[t*16 + i] = base; cursor[t*16 + i] = base; base += loc[i];
  }
  if (t == 1023) rowptr[NNODES] = base;
}

__global__ void k_scatter(const int* __restrict__ src, const int* __restrict__ dst,
                          int* __restrict__ cursor, int* __restrict__ perm){
  int e = blockIdx.x * 256 + threadIdx.x;
  if (e < NEDGES){ int p = atomicAdd(&cursor[dst[e]], 1); perm[p] = src[e]; }
}

// ---- graph-size counts: LDS histogram per block, one global atomic per (block,graph) ----
__global__ __launch_bounds__(256) void k_counts(const int* __restrict__ gid, float* __restrict__ counts){
  __shared__ int h[NGRAPHS];
  int t = threadIdx.x;
  if (t < NGRAPHS) h[t] = 0;
  __syncthreads();
  int base = blockIdx.x * 1024;
  #pragma unroll
  for (int i = 0; i < 4; i++)
    atomicAdd(&h[gid[base + t + i*256]], 1);
  __syncthreads();
  if (t < NGRAPHS && h[t] > 0) atomicAdd(&counts[t], (float)h[t]);
}

// ---------------- fp32 -> bf16 convert (contiguous) ----------------
__global__ void k_cvt(const float* __restrict__ in, unsigned short* __restrict__ out, int n4){
  int i = blockIdx.x * 256 + threadIdx.x;
  if (i >= n4) return;
  float4 v = ((const float4*)in)[i];
  ushort4 o; o.x = f2bf(v.x); o.y = f2bf(v.y); o.z = f2bf(v.z); o.w = f2bf(v.w);
  ((ushort4*)out)[i] = o;
}

// -------- fp32 [K][NN] -> bf16 transposed [NN][K], both W and RW in one launch --------
__global__ __launch_bounds__(256) void k_cvt_t2(const float* __restrict__ W,
                                                const float* __restrict__ RW,
                                                unsigned short* __restrict__ Wt,
                                                unsigned short* __restrict__ RWt,
                                                int K, int NN){
  __shared__ float tile[32][33];
  const float* src = blockIdx.z ? RW : W;
  unsigned short* dst = blockIdx.z ? RWt : Wt;
  int n0 = blockIdx.x * 32, k0 = blockIdx.y * 32;
  int tx = threadIdx.x & 31, ty = threadIdx.x >> 5;   // 32 x 8
  #pragma unroll
  for (int i = 0; i < 4; i++)
    tile[ty + i*8][tx] = src[(size_t)(k0 + ty + i*8) * NN + n0 + tx];
  __syncthreads();
  #pragma unroll
  for (int i = 0; i < 4; i++)
    dst[(size_t)(n0 + ty + i*8) * K + k0 + tx] = f2bf(tile[tx][ty + i*8]);
}

// ------- fused dual bf16 MFMA GEMM (BK=32, counted-vmcnt pipeline, 2-way-free swizzle) -------
// 128x128 tile, BK=32, double-buffered LDS (32KB). Per K-step: issue 4 next-tile
// global_load_lds, s_waitcnt vmcnt(4), s_barrier, ds_read+16 MFMA, s_barrier.
// LDS rows are 64B; swizzle: 16B-slot ^= ((row>>1)&3)<<4. With bank-group = row&1,
// the 16 fragment lanes hit 8 distinct (parity,slot) positions exactly 2x each ->
// 2-way aliasing is FREE (m136). Same XOR on pre-swizzled global source (rule #21).
// W-half epilogue: per-64-col el/er partial dots -> elp/erp (plain stores).
__global__ __launch_bounds__(256) void k_gemm2(const unsigned short* __restrict__ A,
                                               const unsigned short* __restrict__ Wt,
                                               const unsigned short* __restrict__ RWt,
                                               unsigned short* __restrict__ HB,
                                               unsigned short* __restrict__ RB,
                                               const float* __restrict__ al,
                                               const float* __restrict__ ar,
                                               float* __restrict__ elp,
                                               float* __restrict__ erp,
                                               int K, int NN){
  __shared__ unsigned short As[2][128 * 32];
  __shared__ unsigned short Bs[2][128 * 32];
  int t = threadIdx.x;
  int lane = t & 63, w = t >> 6;
  int nx  = gridDim.x;                       // 2*NN/128
  int nwg = nx * gridDim.y;                  // multiple of 8
  int bid = blockIdx.x + blockIdx.y * nx;
  int wg  = (bid & 7) * (nwg >> 3) + (bid >> 3);
  int bx = wg % nx, by = wg / nx;
  int half = nx >> 1;
  bool isW = bx < half;
  const unsigned short* Bt = isW ? Wt : RWt;
  int colB = (isW ? bx : bx - half) * 128;
  int rowA = by * 128;

  int wr = (w >> 1) * 64, wc = (w & 1) * 64;
  int l16 = lane & 15, lhi = lane >> 4;
  f32x4 acc[4][4] = {};

  // staging: 512 chunks of 16B per matrix/tile; thread t -> chunks t and t+256.
  // chunk c: row = c>>2, slot = c&3; global kbyte = (slot<<4) ^ (((row>>1)&3)<<4).
  int srow = t >> 2;                                    // 0..63 (chunk t); +64 for chunk t+256
  int skb  = ((t & 3) << 4) ^ (((srow >> 1) & 3) << 4); // bytes; same for srow+64 (32%4==0)
  const unsigned short* Ap = A  + (size_t)(rowA + srow) * K + (skb >> 1);
  const unsigned short* Bp = Bt + (size_t)(colB + srow) * K + (skb >> 1);
  size_t rstep = (size_t)64 * K;                        // +64 rows

  int nt = K >> 5;
  // prologue: stage tile 0 into buf 0 (4 loads in flight; no drain yet)
  gload_lds16(Ap,         &As[0][t * 8]);
  gload_lds16(Ap + rstep, &As[0][(t + 256) * 8]);
  gload_lds16(Bp,         &Bs[0][t * 8]);
  gload_lds16(Bp + rstep, &Bs[0][(t + 256) * 8]);

  int cur = 0;
  for (int tI = 0; tI < nt; tI++){
    if (tI + 1 < nt){
      int k0n = (tI + 1) << 5;
      gload_lds16(Ap + k0n,         &As[cur ^ 1][t * 8]);
      gload_lds16(Ap + k0n + rstep, &As[cur ^ 1][(t + 256) * 8]);
      gload_lds16(Bp + k0n,         &Bs[cur ^ 1][t * 8]);
      gload_lds16(Bp + k0n + rstep, &Bs[cur ^ 1][(t + 256) * 8]);
      // outstanding = 8; wait until <=4 -> the 4 current-tile loads landed
      asm volatile("s_waitcnt vmcnt(4)" ::: "memory");
    } else {
      asm volatile("s_waitcnt vmcnt(0)" ::: "memory");
    }
    __builtin_amdgcn_s_barrier();            // all waves drained tile tI's loads
    __builtin_amdgcn_sched_barrier(0);       // rule #18: pin reads below the wait
    int kb = lhi * 16;                       // this lane's 16B k-slot
    bf16x8 af[4], bfr[4];
    #pragma unroll
    for (int mi = 0; mi < 4; mi++){
      int row = wr + mi * 16 + l16;
      int off = row * 64 + (kb ^ (((row >> 1) & 3) << 4));
      af[mi] = *(const bf16x8*)((const char*)As[cur] + off);
    }
    #pragma unroll
    for (int ni = 0; ni < 4; ni++){
      int row = wc + ni * 16 + l16;
      int off = row * 64 + (kb ^ (((row >> 1) & 3) << 4));
      bfr[ni] = *(const bf16x8*)((const char*)Bs[cur] + off);
    }
    #pragma unroll
    for (int mi = 0; mi < 4; mi++)
      #pragma unroll
      for (int ni = 0; ni < 4; ni++)
        acc[mi][ni] = __builtin_amdgcn_mfma_f32_16x16x32_bf16(af[mi], bfr[ni], acc[mi][ni], 0, 0, 0);
    // reads consumed (compiler lgkmcnt before MFMAs); next iter may overwrite other buf
    __builtin_amdgcn_s_barrier();
    cur ^= 1;
  }

  unsigned short* C = isW ? HB : RB;
  #pragma unroll
  for (int mi = 0; mi < 4; mi++){
    #pragma unroll
    for (int j = 0; j < 4; j++){
      int r = rowA + wr + mi * 16 + lhi * 4 + j;
      unsigned short* Cp = C + (size_t)r * NN + colB + wc + l16;
      #pragma unroll
      for (int ni = 0; ni < 4; ni++)
        Cp[ni * 16] = f2bf(acc[mi][ni][j]);
    }
  }

  if (isW){
    // el/er partials over this wave's 64 columns; store (no atomics) to elp/erp.
    int G = NN >> 6;                    // 64-col groups across nn
    int g64 = (colB + wc) >> 6;
    float alv[4], arv[4];
    #pragma unroll
    for (int ni = 0; ni < 4; ni++){
      int col = colB + wc + ni * 16 + l16;
      alv[ni] = al[col]; arv[ni] = ar[col];
    }
    #pragma unroll
    for (int mi = 0; mi < 4; mi++){
      #pragma unroll
      for (int j = 0; j < 4; j++){
        float pe = acc[mi][0][j]*alv[0] + acc[mi][1][j]*alv[1]
                 + acc[mi][2][j]*alv[2] + acc[mi][3][j]*alv[3];
        float pr = acc[mi][0][j]*arv[0] + acc[mi][1][j]*arv[1]
                 + acc[mi][2][j]*arv[2] + acc[mi][3][j]*arv[3];
        #pragma unroll
        for (int o = 8; o; o >>= 1){ pe += __shfl_xor(pe, o); pr += __shfl_xor(pr, o); }
        if (l16 == 0){
          int r = rowA + wr + mi * 16 + lhi * 4 + j;
          elp[(size_t)r * G + g64] = pe;
          erp[(size_t)r * G + g64] = pr;
        }
      }
    }
  }
}

// ---- reduce el/er partials: one thread per row; G = nn/64, half per head ----
__global__ void k_elred(const float* __restrict__ elp, const float* __restrict__ erp,
                        float* __restrict__ el, float* __restrict__ er, int G){
  int row = blockIdx.x * 256 + threadIdx.x;
  int half = G >> 1;
  float s0 = 0.f, s1 = 0.f, q0 = 0.f, q1 = 0.f;
  const float* ep = elp + (size_t)row * G;
  const float* rp = erp + (size_t)row * G;
  for (int i = 0; i < half; i++){ s0 += ep[i]; q0 += rp[i]; }
  for (int i = half; i < G; i++){ s1 += ep[i]; q1 += rp[i]; }
  el[row*2] = s0; el[row*2+1] = s1;
  er[row*2] = q0; er[row*2+1] = q1;
}

// ---------------- attention: one wave per destination node; RB(bf16) += attn ----------------
template<int D>
__global__ __launch_bounds__(256) void k_attn(const unsigned short* __restrict__ HB,
                                              unsigned short* __restrict__ RB,
                                              const float* __restrict__ el,
                                              const float* __restrict__ er,
                                              const int* __restrict__ rowptr,
                                              const int* __restrict__ perm){
  constexpr int ITER = (2*D)/256;
  int wid = threadIdx.x >> 6, lane = threadIdx.x & 63;
  int nb = (blockIdx.x & 7) * (NNODES/4/8) + (blockIdx.x >> 3);   // bijective: 4096 = 8*512
  int n = nb * 4 + wid;
  int r0 = rowptr[n], r1 = rowptr[n+1];
  if (r0 == r1) return;   // no in-edges: output = residual already in RB
  float er0 = er[n*2], er1 = er[n*2+1];
  float mx0 = -1e30f, mx1 = -1e30f;
  for (int e = r0 + lane; e < r1; e += 64){
    int s = perm[e];
    mx0 = fmaxf(mx0, leaky(el[s*2]   + er0, 0.2f));
    mx1 = fmaxf(mx1, leaky(el[s*2+1] + er1, 0.2f));
  }
  #pragma unroll
  for (int o = 32; o; o >>= 1){ mx0 = fmaxf(mx0, __shfl_xor(mx0, o)); mx1 = fmaxf(mx1, __shfl_xor(mx1, o)); }
  float sm0 = 0.0f, sm1 = 0.0f;
  for (int e = r0 + lane; e < r1; e += 64){
    int s = perm[e];
    sm0 += expf(leaky(el[s*2]   + er0, 0.2f) - mx0);
    sm1 += expf(leaky(el[s*2+1] + er1, 0.2f) - mx1);
  }
  #pragma unroll
  for (int o = 32; o; o >>= 1){ sm0 += __shfl_xor(sm0, o); sm1 += __shfl_xor(sm1, o); }
  float inv0 = 1.0f / sm0, inv1 = 1.0f / sm1;
  float acc[ITER][4];
  #pragma unroll
  for (int j = 0; j < ITER; j++)
    #pragma unroll
    for (int i = 0; i < 4; i++) acc[j][i] = 0.0f;
  for (int e = r0; e < r1; ++e){
    int s = perm[e];
    float a0 = expf(leaky(el[s*2]   + er0, 0.2f) - mx0) * inv0;
    float a1 = expf(leaky(el[s*2+1] + er1, 0.2f) - mx1) * inv1;
    const unsigned short* hrow = HB + (size_t)s * (2*D);
    #pragma unroll
    for (int j = 0; j < ITER; j++){
      int base = j*256 + lane*4;
      bf16x4 v = *(const bf16x4*)(hrow + base);
      float a = (base < D) ? a0 : a1;
      #pragma unroll
      for (int i = 0; i < 4; i++)
        acc[j][i] += a * bf2f((unsigned short)v[i]);
    }
  }
  unsigned short* rrow = RB + (size_t)n * (2*D);
  #pragma unroll
  for (int j = 0; j < ITER; j++){
    int base = j*256 + lane*4;
    bf16x4 r = *(bf16x4*)(rrow + base);
    ushort4 o;
    o.x = f2bf(bf2f((unsigned short)r[0]) + acc[j][0]);
    o.y = f2bf(bf2f((unsigned short)r[1]) + acc[j][1]);
    o.z = f2bf(bf2f((unsigned short)r[2]) + acc[j][2]);
    o.w = f2bf(bf2f((unsigned short)r[3]) + acc[j][3]);
    *(ushort4*)(rrow + base) = o;
  }
}

// ------- GraphNorm stats (bf16 in): grid (NNODES/128, nn/256); lane owns 4 cols -------
__global__ __launch_bounds__(256) void k_stats(const unsigned short* __restrict__ R, int nn,
                                               float* __restrict__ gsum, float* __restrict__ gsq){
  int t = threadIdx.x, lane = t & 63, w = t >> 6;
  int c = blockIdx.y * 256 + lane * 4;
  const unsigned short* base = R + (size_t)(blockIdx.x * 128 + w) * nn + c;
  float4 s = make_float4(0,0,0,0), q = make_float4(0,0,0,0);
  #pragma unroll 4
  for (int i = 0; i < 32; i++){
    bf16x4 bv = *(const bf16x4*)(base + (size_t)(i * 4) * nn);
    float vx = bf2f((unsigned short)bv[0]), vy = bf2f((unsigned short)bv[1]);
    float vz = bf2f((unsigned short)bv[2]), vw = bf2f((unsigned short)bv[3]);
    s.x += vx; s.y += vy; s.z += vz; s.w += vw;
    q.x += vx*vx; q.y += vy*vy; q.z += vz*vz; q.w += vw*vw;
  }
  __shared__ float4 rs[256], rq[256];
  rs[t] = s; rq[t] = q; __syncthreads();
  if (t < 64){
    float4 a = rs[t], b = rs[t+64], c2 = rs[t+128], d2 = rs[t+192];
    float4 e = rq[t], f = rq[t+64], g2 = rq[t+128], h2 = rq[t+192];
    int cc = blockIdx.y * 256 + t * 4;
    atomicAdd(&gsum[cc+0], a.x+b.x+c2.x+d2.x);
    atomicAdd(&gsum[cc+1], a.y+b.y+c2.y+d2.y);
    atomicAdd(&gsum[cc+2], a.z+b.z+c2.z+d2.z);
    atomicAdd(&gsum[cc+3], a.w+b.w+c2.w+d2.w);
    atomicAdd(&gsq [cc+0], e.x+f.x+g2.x+h2.x);
    atomicAdd(&gsq [cc+1], e.y+f.y+g2.y+h2.y);
    atomicAdd(&gsq [cc+2], e.z+f.z+g2.z+h2.z);
    atomicAdd(&gsq [cc+3], e.w+f.w+g2.w+h2.w);
  }
}

// -- norm apply + leaky + head-mean pool (bf16 in) with INLINE stats finalize --
// grid (NNODES/128, nn/256); params are d-length; column c -> channel c & (d-1).
__global__ __launch_bounds__(256) void k_norm_pool(const unsigned short* __restrict__ R,
                                                   unsigned short* __restrict__ Xn, // bf16 next-layer input (or null)
                                                   const float* __restrict__ gsum,
                                                   const float* __restrict__ gsq,
                                                   const float* __restrict__ gamma,
                                                   const float* __restrict__ beta,
                                                   const float* __restrict__ alpha,
                                                   float* __restrict__ pool, int d, int loff){
  int t = threadIdx.x, lane = t & 63, w = t >> 6;
  int c = blockIdx.y * 256 + lane * 4;
  int cm = c & (d - 1);                    // channel index (d-periodic), 4-aligned
  int nodeb = blockIdx.x * 128;
  int g = blockIdx.x >> 3;                 // 8 row-blocks per graph (1024 nodes/graph)
  int nn = 2 * d;
  const float Minv = 1.0f / (2.0f * (float)NNODES);
  float4 gg = *(const float4*)(gamma + cm);
  float4 bb = *(const float4*)(beta + cm);
  float4 aa = *(const float4*)(alpha + cm);
  float mmv[4], rrv[4];
  #pragma unroll
  for (int i = 0; i < 4; i++){
    float m = (gsum[cm+i] + gsum[cm+i+d]) * Minv;
    float q = (gsq [cm+i] + gsq [cm+i+d]) * Minv;
    float a = (i==0)?aa.x:(i==1)?aa.y:(i==2)?aa.z:aa.w;
    float var = q - a * m * m * (2.0f - a);
    mmv[i] = m; rrv[i] = rsqrtf(var + 1e-5f);
  }
  float am0 = aa.x*mmv[0], am1 = aa.y*mmv[1], am2 = aa.z*mmv[2], am3 = aa.w*mmv[3];
  const unsigned short* base = R + (size_t)(nodeb + w) * nn + c;
  unsigned short* xb = Xn ? (Xn + (size_t)(nodeb + w) * nn + c) : nullptr;
  float4 accp = make_float4(0,0,0,0);
  #pragma unroll 4
  for (int i = 0; i < 32; i++){
    bf16x4 bv = *(const bf16x4*)(base + (size_t)(i * 4) * nn);
    float vx = bf2f((unsigned short)bv[0]), vy = bf2f((unsigned short)bv[1]);
    float vz = bf2f((unsigned short)bv[2]), vw = bf2f((unsigned short)bv[3]);
    float y0 = gg.x*(vx-am0)*rrv[0] + bb.x; y0 = y0 >= 0.f ? y0 : 0.01f*y0;
    float y1 = gg.y*(vy-am1)*rrv[1] + bb.y; y1 = y1 >= 0.f ? y1 : 0.01f*y1;
    float y2 = gg.z*(vz-am2)*rrv[2] + bb.z; y2 = y2 >= 0.f ? y2 : 0.01f*y2;
    float y3 = gg.w*(vw-am3)*rrv[3] + bb.w; y3 = y3 >= 0.f ? y3 : 0.01f*y3;
    if (xb){
      ushort4 o; o.x = f2bf(y0); o.y = f2bf(y1); o.z = f2bf(y2); o.w = f2bf(y3);
      *(ushort4*)(xb + (size_t)(i * 4) * nn) = o;
    }
    accp.x += y0; accp.y += y1; accp.z += y2; accp.w += y3;
  }
  __shared__ float4 red[256];
  red[t] = accp; __syncthreads();
  if (t < 64){
    float4 a = red[t], b = red[t+64], c2 = red[t+128], d2 = red[t+192];
    int cc = blockIdx.y * 256 + t * 4;
    float* pb = pool + g * 896 + loff;
    atomicAdd(&pb[(cc+0) & (d-1)], 0.5f*(a.x+b.x+c2.x+d2.x));
    atomicAdd(&pb[(cc+1) & (d-1)], 0.5f*(a.y+b.y+c2.y+d2.y));
    atomicAdd(&pb[(cc+2) & (d-1)], 0.5f*(a.z+b.z+c2.z+d2.z));
    atomicAdd(&pb[(cc+3) & (d-1)], 0.5f*(a.w+b.w+c2.w+d2.w));
  }
}

__global__ void k_final(const float* __restrict__ pool, const float* __restrict__ counts,
                        float* __restrict__ out){
  int idx = blockIdx.x * 256 + threadIdx.x;
  if (idx >= NGRAPHS * 896) return;
  int g = idx / 896;
  float v = pool[idx] / counts[g];
  out[idx] = v >= 0.0f ? v : 0.01f * v;
}

// ---------------------------------------------------------------------------------------
extern "C" void kernel_launch(void* const* d_in, const int* in_sizes, int n_in,
                              void* d_out, int out_size, void* d_ws, size_t ws_size,
                              hipStream_t stream){
  const float* x0 = (const float*)d_in[0];
  const float *W[3], *AL[3], *AR[3], *RW[3], *GA[3], *BE[3], *ALP[3];
  for (int l = 0; l < 3; l++){
    const int b = 1 + l*7;
    W[l]  = (const float*)d_in[b+0];
    AL[l] = (const float*)d_in[b+1];
    AR[l] = (const float*)d_in[b+2];
    RW[l] = (const float*)d_in[b+3];
    GA[l] = (const float*)d_in[b+4];
    BE[l] = (const float*)d_in[b+5];
    ALP[l]= (const float*)d_in[b+6];
  }
  const int* esrc = (const int*)d_in[22];
  const int* edst = (const int*)d_in[23];
  const int* gid  = (const int*)d_in[24];
  float* out = (float*)d_out;

  char* p = (char*)d_ws;
  auto carve = [&](size_t bytes)->void*{
    void* r = (void*)p; p += (bytes + 255) & ~(size_t)255; return r;
  };
  unsigned short* HB = (unsigned short*)carve((size_t)NNODES * 1024 * 2);  // h bf16 [N, 2d]
  unsigned short* RB = (unsigned short*)carve((size_t)NNODES * 1024 * 2);  // r/out bf16 [N, 2d]
  unsigned short* X0b = (unsigned short*)carve((size_t)NNODES * 128 * 2);  // bf16 layer-0 input
  unsigned short* XA  = (unsigned short*)carve((size_t)NNODES * 256 * 2);  // bf16 y0
  unsigned short* XB  = (unsigned short*)carve((size_t)NNODES * 512 * 2);  // bf16 y1
  unsigned short* Wt  = (unsigned short*)carve((size_t)1024 * 512 * 2);    // bf16 W^T (max)
  unsigned short* RWt = (unsigned short*)carve((size_t)1024 * 512 * 2);    // bf16 resW^T (max)
  float* el     = (float*)carve((size_t)NNODES * 2 * 4);
  float* er     = (float*)carve((size_t)NNODES * 2 * 4);
  float* elp    = (float*)carve((size_t)NNODES * 16 * 4);    // el partials (G<=16)
  float* erp    = (float*)carve((size_t)NNODES * 16 * 4);    // er partials
  int*   deg    = (int*)  carve((size_t)NNODES * 4);
  int*   rowptr = (int*)  carve((size_t)(NNODES + 1) * 4);
  int*   cursor = (int*)  carve((size_t)NNODES * 4);
  int*   perm   = (int*)  carve((size_t)NEDGES * 4);
  float* stats  = (float*)carve(2048 * 4);                   // gsum[1024] | gsq[1024]
  float* pool   = (float*)carve((size_t)NGRAPHS * 896 * 4);
  float* countsF= (float*)carve((size_t)NGRAPHS * 4);
  (void)ws_size; (void)in_sizes; (void)n_in; (void)out_size;

  hipMemsetAsync(deg, 0, NNODES * 4, stream);
  hipMemsetAsync(pool, 0, NGRAPHS * 896 * 4, stream);
  hipMemsetAsync(countsF, 0, NGRAPHS * 4, stream);

  k_deg    <<<NEDGES/256, 256, 0, stream>>>(edst, deg);
  k_scan   <<<1, 1024, 0, stream>>>(deg, rowptr, cursor);
  k_scatter<<<NEDGES/256, 256, 0, stream>>>(esrc, edst, cursor, perm);
  k_counts <<<NNODES/1024, 256, 0, stream>>>(gid, countsF);
  k_cvt    <<<(NNODES*128/4 + 255)/256, 256, 0, stream>>>(x0, X0b, NNODES*128/4);

  const unsigned short* xin = X0b;
  int loff = 0;
  const int dims[3] = {128, 256, 512};
  for (int l = 0; l < 3; l++){
    int d = dims[l], nn = 2*d;
    dim3 gt(nn/32, d/32, 2);
    k_cvt_t2<<<gt, 256, 0, stream>>>(W[l], RW[l], Wt, RWt, d, nn);
    dim3 gg(2*nn/128, NNODES/128);
    k_gemm2<<<gg, 256, 0, stream>>>(xin, Wt, RWt, HB, RB, AL[l], AR[l], elp, erp, d, nn);
    k_elred<<<NNODES/256, 256, 0, stream>>>(elp, erp, el, er, nn >> 6);
    if (d == 128){
      k_attn<128><<<NNODES/4, 256, 0, stream>>>(HB, RB, el, er, rowptr, perm);
    } else if (d == 256){
      k_attn<256><<<NNODES/4, 256, 0, stream>>>(HB, RB, el, er, rowptr, perm);
    } else {
      k_attn<512><<<NNODES/4, 256, 0, stream>>>(HB, RB, el, er, rowptr, perm);
    }
    hipMemsetAsync(stats, 0, 2048 * 4, stream);
    dim3 gs(NNODES/128, nn/256);
    k_stats   <<<gs, 256, 0, stream>>>(RB, nn, stats, stats + 1024);
    unsigned short* xn = (l == 0) ? XA : (l == 1) ? XB : nullptr;
    k_norm_pool<<<gs, 256, 0, stream>>>(RB, xn, stats, stats + 1024, GA[l], BE[l], ALP[l], pool, d, loff);
    xin = xn; loff += d;
  }
  k_final<<<(NGRAPHS*896 + 255)/256, 256, 0, stream>>>(pool, countsF, out);
}